// Round 1
// baseline (2495.657 us; speedup 1.0000x reference)
//
#include <hip/hip_runtime.h>
#include <math.h>

// Problem constants
#define B_ 2
#define T_ 2048
#define E_ 1024
#define H_ 16
#define D_ 64
#define M_ (B_*T_)   // 4096 rows of x flattened

// Y = X @ W^T (+bias). X[M,1024], W[1024,1024] row-major (torch Linear weight).
// mode 0: Y[m*1024+n] = acc + bias[n]          (plain layout, used for out-proj)
// mode 1: head-split write: Y[((b*H+h)*T + t)*D + d]  (for Q/K/V)
__global__ __launch_bounds__(256)
void gemm_xwt(const float* __restrict__ X, const float* __restrict__ W,
              const float* __restrict__ bias, float* __restrict__ Y, int mode)
{
    const int K = 1024, N = 1024;
    __shared__ float As[64][17];   // [row][k] pad to 17 to spread banks
    __shared__ float Bs[64][17];
    const int t  = threadIdx.x;
    const int m0 = blockIdx.y * 64;
    const int n0 = blockIdx.x * 64;
    const int lr = t >> 2;          // 0..63 tile row for loading
    const int lq = (t & 3) << 2;    // 0,4,8,12 k-quad for loading
    const int ty = t >> 4, tx = t & 15;
    float acc[4][4] = {};

    for (int k0 = 0; k0 < K; k0 += 16) {
        __syncthreads();
        float4 av = *(const float4*)(X + (size_t)(m0 + lr) * K + k0 + lq);
        float4 bv = *(const float4*)(W + (size_t)(n0 + lr) * K + k0 + lq);
        As[lr][lq+0] = av.x; As[lr][lq+1] = av.y; As[lr][lq+2] = av.z; As[lr][lq+3] = av.w;
        Bs[lr][lq+0] = bv.x; Bs[lr][lq+1] = bv.y; Bs[lr][lq+2] = bv.z; Bs[lr][lq+3] = bv.w;
        __syncthreads();
        #pragma unroll
        for (int kk = 0; kk < 16; ++kk) {
            float a[4], b[4];
            #pragma unroll
            for (int i = 0; i < 4; ++i) a[i] = As[ty*4+i][kk];
            #pragma unroll
            for (int j = 0; j < 4; ++j) b[j] = Bs[tx*4+j][kk];
            #pragma unroll
            for (int i = 0; i < 4; ++i)
                #pragma unroll
                for (int j = 0; j < 4; ++j)
                    acc[i][j] += a[i] * b[j];
        }
    }
    #pragma unroll
    for (int i = 0; i < 4; ++i) {
        int m = m0 + ty*4 + i;
        #pragma unroll
        for (int j = 0; j < 4; ++j) {
            int n = n0 + tx*4 + j;
            if (mode == 0) {
                Y[(size_t)m * N + n] = acc[i][j] + bias[n];
            } else {
                int b = m >> 11, tt = m & (T_-1);
                int h = n >> 6,  d  = n & (D_-1);
                Y[((size_t)(b*H_ + h) * T_ + tt) * D_ + d] = acc[i][j];
            }
        }
    }
}

// Flash-style causal attention, fp32. Q,K,V in (B,H,T,D). O in (B,T,E) (head concat).
// Grid: (T/64, B*H). 256 threads: thread t -> row r=t/4, col-slice c0=(t&3)*16.
__global__ __launch_bounds__(256)
void attn_fwd(const float* __restrict__ Q, const float* __restrict__ K,
              const float* __restrict__ V, float* __restrict__ O)
{
    __shared__ float Qs[64][65];
    __shared__ float Ks[64][65];
    __shared__ float Vs[64][65];
    __shared__ float Ss[64][65];   // scores -> probabilities
    const int t  = threadIdx.x;
    const int bh = blockIdx.y;            // b*H + h
    const int q0 = blockIdx.x * 64;
    const float scale = 0.125f;           // D^-0.5
    const size_t base = (size_t)bh * T_ * D_;

    // load Q tile (64x64), float4 coalesced
    #pragma unroll
    for (int f = 0; f < 4; ++f) {
        int fi = t + f*256;
        int rr = fi >> 4, dq = (fi & 15) << 2;
        float4 v = *(const float4*)(Q + base + (size_t)(q0 + rr)*D_ + dq);
        Qs[rr][dq] = v.x; Qs[rr][dq+1] = v.y; Qs[rr][dq+2] = v.z; Qs[rr][dq+3] = v.w;
    }

    const int r  = t >> 2;
    const int c0 = (t & 3) * 16;
    float m = -1e30f, lsum = 0.f;
    float acc[16];
    #pragma unroll
    for (int i = 0; i < 16; ++i) acc[i] = 0.f;

    for (int k0 = 0; k0 <= q0; k0 += 64) {
        __syncthreads();   // protects Ks/Vs/Ss reuse and orders initial Qs stores
        #pragma unroll
        for (int f = 0; f < 4; ++f) {
            int fi = t + f*256;
            int rr = fi >> 4, dq = (fi & 15) << 2;
            float4 kv = *(const float4*)(K + base + (size_t)(k0 + rr)*D_ + dq);
            float4 vv = *(const float4*)(V + base + (size_t)(k0 + rr)*D_ + dq);
            Ks[rr][dq] = kv.x; Ks[rr][dq+1] = kv.y; Ks[rr][dq+2] = kv.z; Ks[rr][dq+3] = kv.w;
            Vs[rr][dq] = vv.x; Vs[rr][dq+1] = vv.y; Vs[rr][dq+2] = vv.z; Vs[rr][dq+3] = vv.w;
        }
        __syncthreads();

        // S = Q K^T for this thread's 16 columns
        float s[16];
        #pragma unroll
        for (int j = 0; j < 16; ++j) s[j] = 0.f;
        for (int d = 0; d < 64; ++d) {
            float qv = Qs[r][d];
            #pragma unroll
            for (int j = 0; j < 16; ++j) s[j] += qv * Ks[c0 + j][d];
        }
        // scale + causal mask + tile max
        float tmax = -1e30f;
        #pragma unroll
        for (int j = 0; j < 16; ++j) {
            int kg = k0 + c0 + j;
            s[j] = (kg <= q0 + r) ? s[j] * scale : -1e30f;
            tmax = fmaxf(tmax, s[j]);
        }
        tmax = fmaxf(tmax, __shfl_xor(tmax, 1));
        tmax = fmaxf(tmax, __shfl_xor(tmax, 2));
        float mnew  = fmaxf(m, tmax);
        float alpha = __expf(m - mnew);
        float tsum = 0.f;
        #pragma unroll
        for (int j = 0; j < 16; ++j) {
            float p = __expf(s[j] - mnew);
            Ss[r][c0 + j] = p;
            tsum += p;
        }
        tsum += __shfl_xor(tsum, 1);
        tsum += __shfl_xor(tsum, 2);
        lsum = lsum * alpha + tsum;
        m = mnew;
        __syncthreads();   // P visible to whole row

        // O += P @ V  (this thread: row r, d-cols c0..c0+15)
        #pragma unroll
        for (int i = 0; i < 16; ++i) acc[i] *= alpha;
        for (int j = 0; j < 64; ++j) {
            float p = Ss[r][j];
            #pragma unroll
            for (int i = 0; i < 16; ++i) acc[i] += p * Vs[j][c0 + i];
        }
    }

    // write (B,T,E): O[b][t][h*64 + d]
    const int b = bh >> 4, h = bh & 15;
    const float inv = 1.0f / lsum;
    size_t obase = ((size_t)(b * T_ + q0 + r)) * E_ + h * 64 + c0;
    #pragma unroll
    for (int i = 0; i < 16; ++i) O[obase + i] = acc[i] * inv;
}

extern "C" void kernel_launch(void* const* d_in, const int* in_sizes, int n_in,
                              void* d_out, int out_size, void* d_ws, size_t ws_size,
                              hipStream_t stream) {
    const float* x  = (const float*)d_in[0];
    const float* Wq = (const float*)d_in[1];
    const float* Wk = (const float*)d_in[2];
    const float* Wv = (const float*)d_in[3];
    const float* Wp = (const float*)d_in[4];
    const float* bp = (const float*)d_in[5];
    float* out = (float*)d_out;

    // workspace: Q,K,V in (B,H,T,D) + attn output in (B,T,E); 4 x 16.78 MB = 67 MB
    float* q = (float*)d_ws;
    float* k = q + (size_t)M_ * E_;
    float* v = k + (size_t)M_ * E_;
    float* a = v + (size_t)M_ * E_;

    dim3 blk(256);
    dim3 gg(E_/64, M_/64);            // 16 x 64 tiles
    gemm_xwt<<<gg, blk, 0, stream>>>(x, Wq, nullptr, q, 1);
    gemm_xwt<<<gg, blk, 0, stream>>>(x, Wk, nullptr, k, 1);
    gemm_xwt<<<gg, blk, 0, stream>>>(x, Wv, nullptr, v, 1);
    attn_fwd<<<dim3(T_/64, B_*H_), blk, 0, stream>>>(q, k, v, a);
    gemm_xwt<<<gg, blk, 0, stream>>>(a, Wp, bp, out, 0);
}

// Round 3
// 170.118 us; speedup vs baseline: 14.6701x; 14.6701x over previous
//
#include <hip/hip_runtime.h>

#define T_ 2048
#define E_ 1024
#define H_ 16
#define D_ 64
#define M_ 4096   // B*T

typedef unsigned short ushort_t;
typedef __attribute__((ext_vector_type(8))) short bf16x8;
typedef __attribute__((ext_vector_type(4))) float f32x4;
typedef __attribute__((ext_vector_type(4))) unsigned short u16x4;
typedef __attribute__((ext_vector_type(8))) unsigned short u16x8;

__device__ __forceinline__ ushort_t f2bf(float f) {
  union { float f; unsigned u; } v; v.f = f;
  unsigned r = v.u + 0x7FFFu + ((v.u >> 16) & 1u);
  return (ushort_t)(r >> 16);
}

__device__ __forceinline__ void gl16(const void* g, void* l) {
  __builtin_amdgcn_global_load_lds((const __attribute__((address_space(1))) void*)g,
                                   (__attribute__((address_space(3))) void*)l, 16, 0, 0);
}

// ---------------- f32 -> bf16 ----------------
__global__ __launch_bounds__(256)
void conv_bf16(const float* __restrict__ src, ushort_t* __restrict__ dst, int n) {
  int i = (blockIdx.x * 256 + threadIdx.x) * 8;
  if (i >= n) return;
  float4 a = *(const float4*)(src + i);
  float4 b = *(const float4*)(src + i + 4);
  u16x8 o;
  o[0]=f2bf(a.x); o[1]=f2bf(a.y); o[2]=f2bf(a.z); o[3]=f2bf(a.w);
  o[4]=f2bf(b.x); o[5]=f2bf(b.y); o[6]=f2bf(b.z); o[7]=f2bf(b.w);
  *(u16x8*)(dst + i) = o;
}

// ---------------- shared 128x128x(K=1024) bf16 GEMM core, Y = A @ W^T ----------------
// A[M,1024] bf16 row-major; W[1024,1024] bf16 row-major (torch Linear weight = B^T input).
// LDS chunk-XOR swizzle: row of 64B = 4 chunks of 16B, physical chunk = logical ^ ((row>>1)&3).
__device__ __forceinline__ void gemm_core(const ushort_t* __restrict__ A,
                                          const ushort_t* __restrict__ W,
                                          int m0, int n0,
                                          ushort_t* As, ushort_t* Bs,
                                          f32x4 acc[4][4])
{
  const int t = threadIdx.x;
  const int lane = t & 63, w = t >> 6;
  const int g = lane >> 4, lq = lane & 15;
  const int wr = w >> 1, wc = w & 1;
  const int r0 = t >> 2;                 // staging row, pass 0 (0..63)
  const int c0 = t & 3;                  // staging 16B chunk
  const int ca0 = c0 ^ ((r0 >> 1) & 3);
  const int r1 = r0 + 64;
  const int ca1 = c0 ^ ((r1 >> 1) & 3);

  #pragma unroll
  for (int i = 0; i < 4; ++i)
    #pragma unroll
    for (int j = 0; j < 4; ++j) acc[i][j] = (f32x4){0.f,0.f,0.f,0.f};

  for (int k0 = 0; k0 < 1024; k0 += 32) {
    __syncthreads();
    gl16(A + (size_t)(m0 + r0) * 1024 + k0 + ca0 * 8, As + t * 8);
    gl16(A + (size_t)(m0 + r1) * 1024 + k0 + ca1 * 8, As + 2048 + t * 8);
    gl16(W + (size_t)(n0 + r0) * 1024 + k0 + ca0 * 8, Bs + t * 8);
    gl16(W + (size_t)(n0 + r1) * 1024 + k0 + ca1 * 8, Bs + 2048 + t * 8);
    __syncthreads();   // compiler drains vmcnt before barrier

    bf16x8 af[4], bfr[4];
    #pragma unroll
    for (int mi = 0; mi < 4; ++mi) {
      int row = wr * 64 + mi * 16 + lq;
      int ch = g ^ ((row >> 1) & 3);
      af[mi] = *(const bf16x8*)(As + row * 32 + ch * 8);
    }
    #pragma unroll
    for (int ni = 0; ni < 4; ++ni) {
      int row = wc * 64 + ni * 16 + lq;
      int ch = g ^ ((row >> 1) & 3);
      bfr[ni] = *(const bf16x8*)(Bs + row * 32 + ch * 8);
    }
    #pragma unroll
    for (int mi = 0; mi < 4; ++mi)
      #pragma unroll
      for (int ni = 0; ni < 4; ++ni)
        acc[mi][ni] = __builtin_amdgcn_mfma_f32_16x16x32_bf16(af[mi], bfr[ni], acc[mi][ni], 0, 0, 0);
  }
}

// Fused QKV projection. grid.x 0..23: sel = x>>3 (Q,K,V), n0 = (x&7)*128.
// Q: scaled by D^-0.5, (B,H,T,D). K: (B,H,T,D). V: transposed (B,H,D,T).
__global__ __launch_bounds__(256)
void gemm_qkv(const ushort_t* __restrict__ xb,
              const ushort_t* __restrict__ wqb, const ushort_t* __restrict__ wkb,
              const ushort_t* __restrict__ wvb,
              ushort_t* __restrict__ Qd, ushort_t* __restrict__ Kd, ushort_t* __restrict__ Vd)
{
  __shared__ __align__(16) ushort_t As[4096];
  __shared__ __align__(16) ushort_t Bs[4096];
  const int bx = blockIdx.x;
  const int sel = bx >> 3;
  const int n0 = (bx & 7) * 128;
  const int m0 = blockIdx.y * 128;
  const ushort_t* W = sel == 0 ? wqb : (sel == 1 ? wkb : wvb);
  f32x4 acc[4][4];
  gemm_core(xb, W, m0, n0, As, Bs, acc);

  const int t = threadIdx.x, lane = t & 63, w = t >> 6;
  const int g = lane >> 4, lq = lane & 15, wr = w >> 1, wc = w & 1;
  const float scl = (sel == 0) ? 0.125f : 1.0f;
  ushort_t* dst = sel == 0 ? Qd : (sel == 1 ? Kd : Vd);
  #pragma unroll
  for (int mi = 0; mi < 4; ++mi)
    #pragma unroll
    for (int ni = 0; ni < 4; ++ni)
      #pragma unroll
      for (int r = 0; r < 4; ++r) {
        int m = m0 + wr * 64 + mi * 16 + 4 * g + r;   // C/D: row=(lane>>4)*4+reg
        int n = n0 + wc * 64 + ni * 16 + lq;          //      col=lane&15
        int b = m >> 11, tt = m & (T_ - 1);
        int h = n >> 6, d = n & (D_ - 1);
        ushort_t v = f2bf(acc[mi][ni][r] * scl);
        if (sel < 2) dst[((size_t)(b * H_ + h) * T_ + tt) * D_ + d] = v;
        else         dst[((size_t)(b * H_ + h) * D_ + d) * T_ + tt] = v;
      }
}

// Output projection: out = Ab @ Wp^T + bp (fp32 out)
__global__ __launch_bounds__(256)
void gemm_out(const ushort_t* __restrict__ Ab, const ushort_t* __restrict__ wpb,
              const float* __restrict__ bias, float* __restrict__ out)
{
  __shared__ __align__(16) ushort_t As[4096];
  __shared__ __align__(16) ushort_t Bs[4096];
  const int n0 = blockIdx.x * 128;
  const int m0 = blockIdx.y * 128;
  f32x4 acc[4][4];
  gemm_core(Ab, wpb, m0, n0, As, Bs, acc);

  const int t = threadIdx.x, lane = t & 63, w = t >> 6;
  const int g = lane >> 4, lq = lane & 15, wr = w >> 1, wc = w & 1;
  #pragma unroll
  for (int mi = 0; mi < 4; ++mi)
    #pragma unroll
    for (int ni = 0; ni < 4; ++ni)
      #pragma unroll
      for (int r = 0; r < 4; ++r) {
        int m = m0 + wr * 64 + mi * 16 + 4 * g + r;
        int n = n0 + wc * 64 + ni * 16 + lq;
        out[(size_t)m * E_ + n] = acc[mi][ni][r] + bias[n];
      }
}

// ---------------- MFMA flash attention (causal), swapped QK^T ----------------
// Q,K: (B,H,T,D) bf16 (Q pre-scaled). Vt: (B,H,D,T) bf16. O: (B,T,E) bf16.
// Block: 256 thr / 4 waves; Q-tile 64 rows; wave w owns q rows 16w..16w+15.
__global__ __launch_bounds__(256)
void attn_mfma(const ushort_t* __restrict__ Q, const ushort_t* __restrict__ K,
               const ushort_t* __restrict__ Vt, ushort_t* __restrict__ O)
{
  __shared__ __align__(16) ushort_t Qs[64 * 64];
  __shared__ __align__(16) ushort_t Ks[64 * 64];
  __shared__ __align__(16) ushort_t Vs[64 * 64];
  __shared__ __align__(16) ushort_t Ps[64 * 72];   // padded rows: 2-way max on reads
  const int t = threadIdx.x, w = t >> 6, lane = t & 63;
  const int g = lane >> 4, lq = lane & 15;
  const int bh = blockIdx.y;
  const int q0 = blockIdx.x * 64;
  const size_t qkbase = (size_t)bh * T_ * D_;
  const size_t vbase  = (size_t)bh * D_ * T_;

  { // stage Q tile, chunk-swizzled source so linear LDS + swizzled reads agree
    int row = t >> 3, c = t & 7;
    int cs = c ^ (row & 7);
    int row1 = row + 32, cs1 = c ^ (row1 & 7);
    gl16(Q + qkbase + (size_t)(q0 + row) * D_ + cs * 8, Qs + t * 8);
    gl16(Q + qkbase + (size_t)(q0 + row1) * D_ + cs1 * 8, Qs + 2048 + t * 8);
  }
  __syncthreads();
  const int qrow = 16 * w + lq;
  const int qg = q0 + qrow;
  bf16x8 qf0 = *(const bf16x8*)(Qs + qrow * 64 + ((g ^ (qrow & 7)) * 8));
  bf16x8 qf1 = *(const bf16x8*)(Qs + qrow * 64 + (((4 + g) ^ (qrow & 7)) * 8));

  f32x4 acc[4];
  #pragma unroll
  for (int db = 0; db < 4; ++db) acc[db] = (f32x4){0.f,0.f,0.f,0.f};
  float mrow = -1e30f, lrow = 0.f;

  const int nt = q0 / 64 + 1;
  for (int kt = 0; kt < nt; ++kt) {
    const int k0 = kt * 64;
    __syncthreads();                       // prev tile fully consumed
    {
      int row = t >> 3, c = t & 7;
      int cs = c ^ (row & 7);
      int row1 = row + 32, cs1 = c ^ (row1 & 7);
      gl16(K + qkbase + (size_t)(k0 + row) * D_ + cs * 8, Ks + t * 8);
      gl16(K + qkbase + (size_t)(k0 + row1) * D_ + cs1 * 8, Ks + 2048 + t * 8);
      gl16(Vt + vbase + (size_t)row * T_ + k0 + cs * 8, Vs + t * 8);
      gl16(Vt + vbase + (size_t)row1 * T_ + k0 + cs1 * 8, Vs + 2048 + t * 8);
    }
    __syncthreads();

    // S^T = K·Q^T: lane holds q-row qg, k = k0 + kb*16 + 4g + r
    f32x4 st[4];
    #pragma unroll
    for (int kb = 0; kb < 4; ++kb) {
      int krow = kb * 16 + lq;
      bf16x8 ka0 = *(const bf16x8*)(Ks + krow * 64 + ((g ^ (krow & 7)) * 8));
      bf16x8 ka1 = *(const bf16x8*)(Ks + krow * 64 + (((4 + g) ^ (krow & 7)) * 8));
      f32x4 z = (f32x4){0.f,0.f,0.f,0.f};
      z = __builtin_amdgcn_mfma_f32_16x16x32_bf16(ka0, qf0, z, 0, 0, 0);
      z = __builtin_amdgcn_mfma_f32_16x16x32_bf16(ka1, qf1, z, 0, 0, 0);
      st[kb] = z;
    }
    if (kt == nt - 1) {                    // only the diagonal tile needs masking
      #pragma unroll
      for (int kb = 0; kb < 4; ++kb)
        #pragma unroll
        for (int r = 0; r < 4; ++r) {
          int kg = k0 + kb * 16 + 4 * g + r;
          if (kg > qg) st[kb][r] = -1e30f;
        }
    }
    float tmax = -1e30f;
    #pragma unroll
    for (int kb = 0; kb < 4; ++kb)
      #pragma unroll
      for (int r = 0; r < 4; ++r) tmax = fmaxf(tmax, st[kb][r]);
    tmax = fmaxf(tmax, __shfl_xor(tmax, 16));
    tmax = fmaxf(tmax, __shfl_xor(tmax, 32));
    float mnew = fmaxf(mrow, tmax);
    float alpha = __expf(mrow - mnew);
    float tsum = 0.f;
    #pragma unroll
    for (int kb = 0; kb < 4; ++kb) {
      u16x4 pk;
      #pragma unroll
      for (int r = 0; r < 4; ++r) {
        float p = __expf(st[kb][r] - mnew);
        tsum += p;
        pk[r] = f2bf(p);
      }
      *(u16x4*)(Ps + qrow * 72 + kb * 16 + 4 * g) = pk;   // P[q][k], 8B packed
    }
    tsum += __shfl_xor(tsum, 16);
    tsum += __shfl_xor(tsum, 32);
    lrow = lrow * alpha + tsum;
    mrow = mnew;

    asm volatile("s_waitcnt lgkmcnt(0)" ::: "memory");    // Ps writes visible (same wave)
    bf16x8 pa0 = *(const bf16x8*)(Ps + qrow * 72 + g * 8);
    bf16x8 pa1 = *(const bf16x8*)(Ps + qrow * 72 + 32 + g * 8);
    float al[4];
    #pragma unroll
    for (int r = 0; r < 4; ++r) al[r] = __shfl(alpha, 4 * g + r);  // alpha for acc's q-rows
    #pragma unroll
    for (int db = 0; db < 4; ++db) {
      #pragma unroll
      for (int r = 0; r < 4; ++r) acc[db][r] *= al[r];
      int vrow = db * 16 + lq;
      bf16x8 vb0 = *(const bf16x8*)(Vs + vrow * 64 + ((g ^ (vrow & 7)) * 8));
      bf16x8 vb1 = *(const bf16x8*)(Vs + vrow * 64 + (((4 + g) ^ (vrow & 7)) * 8));
      acc[db] = __builtin_amdgcn_mfma_f32_16x16x32_bf16(pa0, vb0, acc[db], 0, 0, 0);
      acc[db] = __builtin_amdgcn_mfma_f32_16x16x32_bf16(pa1, vb1, acc[db], 0, 0, 0);
    }
  }

  float linv = 1.0f / lrow;
  float li[4];
  #pragma unroll
  for (int r = 0; r < 4; ++r) li[r] = __shfl(linv, 4 * g + r);
  const int b = bh >> 4, h = bh & 15;
  #pragma unroll
  for (int db = 0; db < 4; ++db)
    #pragma unroll
    for (int r = 0; r < 4; ++r) {
      int m = q0 + 16 * w + 4 * g + r;
      O[((size_t)(b * T_ + m)) * E_ + h * 64 + db * 16 + lq] = f2bf(acc[db][r] * li[r]);
    }
}

extern "C" void kernel_launch(void* const* d_in, const int* in_sizes, int n_in,
                              void* d_out, int out_size, void* d_ws, size_t ws_size,
                              hipStream_t stream) {
  const float* x  = (const float*)d_in[0];
  const float* Wq = (const float*)d_in[1];
  const float* Wk = (const float*)d_in[2];
  const float* Wv = (const float*)d_in[3];
  const float* Wp = (const float*)d_in[4];
  const float* bp = (const float*)d_in[5];
  float* out = (float*)d_out;

  ushort_t* ws  = (ushort_t*)d_ws;
  ushort_t* xb  = ws;                            // 4M elems
  ushort_t* wqb = xb  + (size_t)M_ * E_;         // 1M each
  ushort_t* wkb = wqb + (size_t)E_ * E_;
  ushort_t* wvb = wkb + (size_t)E_ * E_;
  ushort_t* wpb = wvb + (size_t)E_ * E_;
  ushort_t* Qb  = wpb + (size_t)E_ * E_;         // 4M each
  ushort_t* Kb  = Qb  + (size_t)M_ * E_;
  ushort_t* Vb  = Kb  + (size_t)M_ * E_;
  ushort_t* Ab  = Vb  + (size_t)M_ * E_;

  conv_bf16<<<2048, 256, 0, stream>>>(x,  xb,  M_ * E_);
  conv_bf16<<<512,  256, 0, stream>>>(Wq, wqb, E_ * E_);
  conv_bf16<<<512,  256, 0, stream>>>(Wk, wkb, E_ * E_);
  conv_bf16<<<512,  256, 0, stream>>>(Wv, wvb, E_ * E_);
  conv_bf16<<<512,  256, 0, stream>>>(Wp, wpb, E_ * E_);

  gemm_qkv<<<dim3(24, 32), 256, 0, stream>>>(xb, wqb, wkb, wvb, Qb, Kb, Vb);
  attn_mfma<<<dim3(32, 32), 256, 0, stream>>>(Qb, Kb, Vb, Ab);
  gemm_out<<<dim3(8, 32), 256, 0, stream>>>(Ab, wpb, bp, out);
}

// Round 5
// 147.513 us; speedup vs baseline: 16.9182x; 1.1532x over previous
//
#include <hip/hip_runtime.h>

#define T_ 2048
#define E_ 1024
#define H_ 16
#define D_ 64
#define M_ 4096   // B*T

typedef unsigned short ushort_t;
typedef __attribute__((ext_vector_type(8))) short bf16x8;
typedef __attribute__((ext_vector_type(4))) float f32x4;
typedef __attribute__((ext_vector_type(4))) unsigned short u16x4;
typedef __attribute__((ext_vector_type(8))) unsigned short u16x8;

__device__ __forceinline__ ushort_t f2bf(float f) {
  union { float f; unsigned u; } v; v.f = f;
  unsigned r = v.u + 0x7FFFu + ((v.u >> 16) & 1u);
  return (ushort_t)(r >> 16);
}

__device__ __forceinline__ void gl16(const void* g, void* l) {
  __builtin_amdgcn_global_load_lds((const __attribute__((address_space(1))) void*)g,
                                   (__attribute__((address_space(3))) void*)l, 16, 0, 0);
}

// ---------------- all f32->bf16 conversions in ONE launch ----------------
// blocks 0..2047: x (4M elems). 2048+512*i, i=0..3: Wq,Wk,Wv,Wp (1M each).
__global__ __launch_bounds__(256)
void conv_all(const float* __restrict__ x,  const float* __restrict__ wq,
              const float* __restrict__ wk, const float* __restrict__ wv,
              const float* __restrict__ wp,
              ushort_t* __restrict__ xb,  ushort_t* __restrict__ wqb,
              ushort_t* __restrict__ wkb, ushort_t* __restrict__ wvb,
              ushort_t* __restrict__ wpb)
{
  const int id = blockIdx.x;
  const float* s; ushort_t* d; size_t off;
  if (id < 2048) { s = x; d = xb; off = (size_t)id * 2048; }
  else {
    int wsel = (id - 2048) >> 9, wid = (id - 2048) & 511;
    off = (size_t)wid * 2048;
    s = wsel == 0 ? wq : wsel == 1 ? wk : wsel == 2 ? wv : wp;
    d = wsel == 0 ? wqb : wsel == 1 ? wkb : wsel == 2 ? wvb : wpb;
  }
  size_t i = off + (size_t)threadIdx.x * 8;
  float4 a = *(const float4*)(s + i);
  float4 b = *(const float4*)(s + i + 4);
  u16x8 o;
  o[0]=f2bf(a.x); o[1]=f2bf(a.y); o[2]=f2bf(a.z); o[3]=f2bf(a.w);
  o[4]=f2bf(b.x); o[5]=f2bf(b.y); o[6]=f2bf(b.z); o[7]=f2bf(b.w);
  *(u16x8*)(d + i) = o;
}

// ---------------- 128x128x(K=1024) bf16 GEMM core, Y = A @ W^T ----------------
__device__ __forceinline__ void gemm_core(const ushort_t* __restrict__ A,
                                          const ushort_t* __restrict__ W,
                                          int m0, int n0,
                                          ushort_t* As, ushort_t* Bs,
                                          f32x4 acc[4][4])
{
  const int t = threadIdx.x;
  const int lane = t & 63, w = t >> 6;
  const int g = lane >> 4, lq = lane & 15;
  const int wr = w >> 1, wc = w & 1;
  const int r0 = t >> 2;
  const int c0 = t & 3;
  const int ca0 = c0 ^ ((r0 >> 1) & 3);
  const int r1 = r0 + 64;
  const int ca1 = c0 ^ ((r1 >> 1) & 3);

  #pragma unroll
  for (int i = 0; i < 4; ++i)
    #pragma unroll
    for (int j = 0; j < 4; ++j) acc[i][j] = (f32x4){0.f,0.f,0.f,0.f};

  for (int k0 = 0; k0 < 1024; k0 += 32) {
    __syncthreads();
    gl16(A + (size_t)(m0 + r0) * 1024 + k0 + ca0 * 8, As + t * 8);
    gl16(A + (size_t)(m0 + r1) * 1024 + k0 + ca1 * 8, As + 2048 + t * 8);
    gl16(W + (size_t)(n0 + r0) * 1024 + k0 + ca0 * 8, Bs + t * 8);
    gl16(W + (size_t)(n0 + r1) * 1024 + k0 + ca1 * 8, Bs + 2048 + t * 8);
    __syncthreads();

    bf16x8 af[4], bfr[4];
    #pragma unroll
    for (int mi = 0; mi < 4; ++mi) {
      int row = wr * 64 + mi * 16 + lq;
      int ch = g ^ ((row >> 1) & 3);
      af[mi] = *(const bf16x8*)(As + row * 32 + ch * 8);
    }
    #pragma unroll
    for (int ni = 0; ni < 4; ++ni) {
      int row = wc * 64 + ni * 16 + lq;
      int ch = g ^ ((row >> 1) & 3);
      bfr[ni] = *(const bf16x8*)(Bs + row * 32 + ch * 8);
    }
    __builtin_amdgcn_s_setprio(1);
    #pragma unroll
    for (int mi = 0; mi < 4; ++mi)
      #pragma unroll
      for (int ni = 0; ni < 4; ++ni)
        acc[mi][ni] = __builtin_amdgcn_mfma_f32_16x16x32_bf16(af[mi], bfr[ni], acc[mi][ni], 0, 0, 0);
    __builtin_amdgcn_s_setprio(0);
  }
}

// Fused QKV projection. grid.x 0..23: sel = x>>3 (Q,K,V), n0 = (x&7)*128.
__global__ __launch_bounds__(256)
void gemm_qkv(const ushort_t* __restrict__ xb,
              const ushort_t* __restrict__ wqb, const ushort_t* __restrict__ wkb,
              const ushort_t* __restrict__ wvb,
              ushort_t* __restrict__ Qd, ushort_t* __restrict__ Kd, ushort_t* __restrict__ Vd)
{
  __shared__ __align__(16) ushort_t As[4096];
  __shared__ __align__(16) ushort_t Bs[4096];
  const int bx = blockIdx.x;
  const int sel = bx >> 3;
  const int n0 = (bx & 7) * 128;
  const int m0 = blockIdx.y * 128;
  const ushort_t* W = sel == 0 ? wqb : (sel == 1 ? wkb : wvb);
  f32x4 acc[4][4];
  gemm_core(xb, W, m0, n0, As, Bs, acc);

  const int t = threadIdx.x, lane = t & 63, w = t >> 6;
  const int g = lane >> 4, lq = lane & 15, wr = w >> 1, wc = w & 1;
  const float scl = (sel == 0) ? 0.125f : 1.0f;
  ushort_t* dst = sel == 0 ? Qd : (sel == 1 ? Kd : Vd);
  #pragma unroll
  for (int mi = 0; mi < 4; ++mi)
    #pragma unroll
    for (int ni = 0; ni < 4; ++ni)
      #pragma unroll
      for (int r = 0; r < 4; ++r) {
        int m = m0 + wr * 64 + mi * 16 + 4 * g + r;
        int n = n0 + wc * 64 + ni * 16 + lq;
        int b = m >> 11, tt = m & (T_ - 1);
        int h = n >> 6, d = n & (D_ - 1);
        ushort_t v = f2bf(acc[mi][ni][r] * scl);
        if (sel < 2) dst[((size_t)(b * H_ + h) * T_ + tt) * D_ + d] = v;
        else         dst[((size_t)(b * H_ + h) * D_ + d) * T_ + tt] = v;
      }
}

// Output projection, 64x128 tiles: out = Ab @ Wp^T + bp (fp32). grid (8, 64).
__global__ __launch_bounds__(256)
void gemm_out64(const ushort_t* __restrict__ Ab, const ushort_t* __restrict__ wpb,
                const float* __restrict__ bias, float* __restrict__ out)
{
  __shared__ __align__(16) ushort_t As[2048];   // 64 x 32
  __shared__ __align__(16) ushort_t Bs[4096];   // 128 x 32
  const int t = threadIdx.x, lane = t & 63, w = t >> 6;
  const int g = lane >> 4, lq = lane & 15;
  const int n0 = blockIdx.x * 128;
  const int m0 = blockIdx.y * 64;
  const int r0 = t >> 2, c0 = t & 3;
  const int ca0 = c0 ^ ((r0 >> 1) & 3);
  const int r1 = r0 + 64;
  const int ca1 = c0 ^ ((r1 >> 1) & 3);

  f32x4 acc[4][2];
  #pragma unroll
  for (int i = 0; i < 4; ++i) { acc[i][0] = (f32x4){0.f,0.f,0.f,0.f}; acc[i][1] = (f32x4){0.f,0.f,0.f,0.f}; }

  for (int k0 = 0; k0 < 1024; k0 += 32) {
    __syncthreads();
    gl16(Ab  + (size_t)(m0 + r0) * 1024 + k0 + ca0 * 8, As + t * 8);
    gl16(wpb + (size_t)(n0 + r0) * 1024 + k0 + ca0 * 8, Bs + t * 8);
    gl16(wpb + (size_t)(n0 + r1) * 1024 + k0 + ca1 * 8, Bs + 2048 + t * 8);
    __syncthreads();

    bf16x8 af[4], bfr[2];
    #pragma unroll
    for (int mi = 0; mi < 4; ++mi) {
      int row = mi * 16 + lq;
      int ch = g ^ ((row >> 1) & 3);
      af[mi] = *(const bf16x8*)(As + row * 32 + ch * 8);
    }
    #pragma unroll
    for (int ni = 0; ni < 2; ++ni) {
      int row = w * 32 + ni * 16 + lq;
      int ch = g ^ ((row >> 1) & 3);
      bfr[ni] = *(const bf16x8*)(Bs + row * 32 + ch * 8);
    }
    __builtin_amdgcn_s_setprio(1);
    #pragma unroll
    for (int mi = 0; mi < 4; ++mi)
      #pragma unroll
      for (int ni = 0; ni < 2; ++ni)
        acc[mi][ni] = __builtin_amdgcn_mfma_f32_16x16x32_bf16(af[mi], bfr[ni], acc[mi][ni], 0, 0, 0);
    __builtin_amdgcn_s_setprio(0);
  }
  #pragma unroll
  for (int mi = 0; mi < 4; ++mi)
    #pragma unroll
    for (int ni = 0; ni < 2; ++ni)
      #pragma unroll
      for (int r = 0; r < 4; ++r) {
        int m = m0 + mi * 16 + 4 * g + r;
        int n = n0 + w * 32 + ni * 16 + lq;
        out[(size_t)m * E_ + n] = acc[mi][ni][r] + bias[n];
      }
}

// ---------------- MFMA flash attention v2 ----------------
// QBLK=128 (4 waves x 32 q-rows), KVBLK=64, double-buffered K/V, Q in regs.
// Q,K: (B,H,T,D) bf16 (Q pre-scaled). Vt: (B,H,D,T). O: (B,T,E) bf16.
__global__ __launch_bounds__(256)
void attn_mfma(const ushort_t* __restrict__ Q, const ushort_t* __restrict__ K,
               const ushort_t* __restrict__ Vt, ushort_t* __restrict__ O)
{
  __shared__ __align__(16) ushort_t Ks[2][4096];
  __shared__ __align__(16) ushort_t Vs[2][4096];
  __shared__ __align__(16) ushort_t Ps[128 * 72];
  const int t = threadIdx.x, w = t >> 6, lane = t & 63;
  const int g = lane >> 4, lq = lane & 15;
  const int bh = blockIdx.y;
  const int qt = 15 - ((blockIdx.x + bh) & 15);   // balance: mix tile sizes per CU, big first
  const int q0 = qt * 128;
  const size_t qkbase = (size_t)bh * T_ * D_;
  const size_t vbase  = (size_t)bh * D_ * T_;

  const int srow = t >> 3, sc = t & 7;
  const int cs0 = sc ^ (srow & 7);
  const int srow1 = srow + 32;
  const int cs1 = sc ^ (srow1 & 7);

  // Q fragments directly to registers (read once; no LDS, no barrier)
  const int rowA = 32 * w + lq, rowB = rowA + 16;
  const int qgA = q0 + rowA, qgB = q0 + rowB;
  const bf16x8 qA0 = *(const bf16x8*)(Q + qkbase + (size_t)qgA * D_ + g * 8);
  const bf16x8 qA1 = *(const bf16x8*)(Q + qkbase + (size_t)qgA * D_ + 32 + g * 8);
  const bf16x8 qB0 = *(const bf16x8*)(Q + qkbase + (size_t)qgB * D_ + g * 8);
  const bf16x8 qB1 = *(const bf16x8*)(Q + qkbase + (size_t)qgB * D_ + 32 + g * 8);

  f32x4 accA[4], accB[4];
  #pragma unroll
  for (int db = 0; db < 4; ++db) { accA[db] = (f32x4){0.f,0.f,0.f,0.f}; accB[db] = (f32x4){0.f,0.f,0.f,0.f}; }
  float mA = -1e30f, lA = 0.f, mB = -1e30f, lB = 0.f;

  const int nt = 2 * qt + 2;

  // prologue: stage tile 0 into buf 0
  {
    gl16(K + qkbase + (size_t)srow  * D_ + cs0 * 8, &Ks[0][t * 8]);
    gl16(K + qkbase + (size_t)srow1 * D_ + cs1 * 8, &Ks[0][2048 + t * 8]);
    gl16(Vt + vbase + (size_t)srow  * T_ + cs0 * 8, &Vs[0][t * 8]);
    gl16(Vt + vbase + (size_t)srow1 * T_ + cs1 * 8, &Vs[0][2048 + t * 8]);
  }
  __syncthreads();

  for (int kt = 0; kt < nt; ++kt) {
    const int cur = kt & 1;
    const int k0 = kt * 64;
    if (kt + 1 < nt) {                       // prefetch next tile into other buffer
      const int kn = (kt + 1) * 64;
      gl16(K + qkbase + (size_t)(kn + srow)  * D_ + cs0 * 8, &Ks[cur ^ 1][t * 8]);
      gl16(K + qkbase + (size_t)(kn + srow1) * D_ + cs1 * 8, &Ks[cur ^ 1][2048 + t * 8]);
      gl16(Vt + vbase + (size_t)srow  * T_ + kn + cs0 * 8, &Vs[cur ^ 1][t * 8]);
      gl16(Vt + vbase + (size_t)srow1 * T_ + kn + cs1 * 8, &Vs[cur ^ 1][2048 + t * 8]);
    }
    const ushort_t* kb_ = &Ks[cur][0];
    const ushort_t* vb_ = &Vs[cur][0];

    // S^T = K . Q^T (each K fragment feeds both q sub-blocks)
    f32x4 stA[4], stB[4];
    __builtin_amdgcn_s_setprio(1);
    #pragma unroll
    for (int kb = 0; kb < 4; ++kb) {
      int krow = kb * 16 + lq;
      bf16x8 ka0 = *(const bf16x8*)(kb_ + krow * 64 + ((g ^ (krow & 7)) * 8));
      bf16x8 ka1 = *(const bf16x8*)(kb_ + krow * 64 + (((4 + g) ^ (krow & 7)) * 8));
      f32x4 zA = (f32x4){0.f,0.f,0.f,0.f};
      zA = __builtin_amdgcn_mfma_f32_16x16x32_bf16(ka0, qA0, zA, 0, 0, 0);
      zA = __builtin_amdgcn_mfma_f32_16x16x32_bf16(ka1, qA1, zA, 0, 0, 0);
      stA[kb] = zA;
      f32x4 zB = (f32x4){0.f,0.f,0.f,0.f};
      zB = __builtin_amdgcn_mfma_f32_16x16x32_bf16(ka0, qB0, zB, 0, 0, 0);
      zB = __builtin_amdgcn_mfma_f32_16x16x32_bf16(ka1, qB1, zB, 0, 0, 0);
      stB[kb] = zB;
    }
    __builtin_amdgcn_s_setprio(0);

    if (kt >= nt - 2) {                      // only diagonal-adjacent tiles mask
      #pragma unroll
      for (int kb = 0; kb < 4; ++kb)
        #pragma unroll
        for (int r = 0; r < 4; ++r) {
          int kg = k0 + kb * 16 + 4 * g + r;
          if (kg > qgA) stA[kb][r] = -1e30f;
          if (kg > qgB) stB[kb][r] = -1e30f;
        }
    }

    float tmA = -1e30f, tmB = -1e30f;
    #pragma unroll
    for (int kb = 0; kb < 4; ++kb)
      #pragma unroll
      for (int r = 0; r < 4; ++r) { tmA = fmaxf(tmA, stA[kb][r]); tmB = fmaxf(tmB, stB[kb][r]); }
    tmA = fmaxf(tmA, __shfl_xor(tmA, 16)); tmA = fmaxf(tmA, __shfl_xor(tmA, 32));
    tmB = fmaxf(tmB, __shfl_xor(tmB, 16)); tmB = fmaxf(tmB, __shfl_xor(tmB, 32));
    float mnA = fmaxf(mA, tmA), mnB = fmaxf(mB, tmB);
    float alA = __expf(mA - mnA), alB = __expf(mB - mnB);
    float tsA = 0.f, tsB = 0.f;
    #pragma unroll
    for (int kb = 0; kb < 4; ++kb) {
      u16x4 pkA, pkB;
      #pragma unroll
      for (int r = 0; r < 4; ++r) {
        float pA = __expf(stA[kb][r] - mnA); tsA += pA; pkA[r] = f2bf(pA);
        float pB = __expf(stB[kb][r] - mnB); tsB += pB; pkB[r] = f2bf(pB);
      }
      *(u16x4*)(Ps + rowA * 72 + kb * 16 + 4 * g) = pkA;
      *(u16x4*)(Ps + rowB * 72 + kb * 16 + 4 * g) = pkB;
    }
    tsA += __shfl_xor(tsA, 16); tsA += __shfl_xor(tsA, 32);
    tsB += __shfl_xor(tsB, 16); tsB += __shfl_xor(tsB, 32);
    lA = lA * alA + tsA; mA = mnA;
    lB = lB * alB + tsB; mB = mnB;

    asm volatile("s_waitcnt lgkmcnt(0)" ::: "memory");   // own-wave Ps writes visible
    bf16x8 paA0 = *(const bf16x8*)(Ps + rowA * 72 + g * 8);
    bf16x8 paA1 = *(const bf16x8*)(Ps + rowA * 72 + 32 + g * 8);
    bf16x8 paB0 = *(const bf16x8*)(Ps + rowB * 72 + g * 8);
    bf16x8 paB1 = *(const bf16x8*)(Ps + rowB * 72 + 32 + g * 8);
    float alAr[4], alBr[4];
    #pragma unroll
    for (int r = 0; r < 4; ++r) { alAr[r] = __shfl(alA, 4 * g + r); alBr[r] = __shfl(alB, 4 * g + r); }

    __builtin_amdgcn_s_setprio(1);
    #pragma unroll
    for (int db = 0; db < 4; ++db) {
      int vrow = db * 16 + lq;
      bf16x8 vb0 = *(const bf16x8*)(vb_ + vrow * 64 + ((g ^ (vrow & 7)) * 8));
      bf16x8 vb1 = *(const bf16x8*)(vb_ + vrow * 64 + (((4 + g) ^ (vrow & 7)) * 8));
      #pragma unroll
      for (int r = 0; r < 4; ++r) { accA[db][r] *= alAr[r]; accB[db][r] *= alBr[r]; }
      accA[db] = __builtin_amdgcn_mfma_f32_16x16x32_bf16(paA0, vb0, accA[db], 0, 0, 0);
      accA[db] = __builtin_amdgcn_mfma_f32_16x16x32_bf16(paA1, vb1, accA[db], 0, 0, 0);
      accB[db] = __builtin_amdgcn_mfma_f32_16x16x32_bf16(paB0, vb0, accB[db], 0, 0, 0);
      accB[db] = __builtin_amdgcn_mfma_f32_16x16x32_bf16(paB1, vb1, accB[db], 0, 0, 0);
    }
    __builtin_amdgcn_s_setprio(0);

    __syncthreads();   // drains prefetch vmcnt + all LDS reads before buffer reuse
  }

  float invA = 1.0f / lA, invB = 1.0f / lB;
  float liA[4], liB[4];
  #pragma unroll
  for (int r = 0; r < 4; ++r) { liA[r] = __shfl(invA, 4 * g + r); liB[r] = __shfl(invB, 4 * g + r); }
  const int b = bh >> 4, h = bh & 15;
  #pragma unroll
  for (int db = 0; db < 4; ++db)
    #pragma unroll
    for (int r = 0; r < 4; ++r) {
      int mAo = q0 + 32 * w + 4 * g + r;
      int mBo = mAo + 16;
      O[((size_t)(b * T_ + mAo)) * E_ + h * 64 + db * 16 + lq] = f2bf(accA[db][r] * liA[r]);
      O[((size_t)(b * T_ + mBo)) * E_ + h * 64 + db * 16 + lq] = f2bf(accB[db][r] * liB[r]);
    }
}

extern "C" void kernel_launch(void* const* d_in, const int* in_sizes, int n_in,
                              void* d_out, int out_size, void* d_ws, size_t ws_size,
                              hipStream_t stream) {
  const float* x  = (const float*)d_in[0];
  const float* Wq = (const float*)d_in[1];
  const float* Wk = (const float*)d_in[2];
  const float* Wv = (const float*)d_in[3];
  const float* Wp = (const float*)d_in[4];
  const float* bp = (const float*)d_in[5];
  float* out = (float*)d_out;

  ushort_t* ws  = (ushort_t*)d_ws;
  ushort_t* xb  = ws;
  ushort_t* wqb = xb  + (size_t)M_ * E_;
  ushort_t* wkb = wqb + (size_t)E_ * E_;
  ushort_t* wvb = wkb + (size_t)E_ * E_;
  ushort_t* wpb = wvb + (size_t)E_ * E_;
  ushort_t* Qb  = wpb + (size_t)E_ * E_;
  ushort_t* Kb  = Qb  + (size_t)M_ * E_;
  ushort_t* Vb  = Kb  + (size_t)M_ * E_;
  ushort_t* Ab  = Vb  + (size_t)M_ * E_;

  conv_all<<<4096, 256, 0, stream>>>(x, Wq, Wk, Wv, Wp, xb, wqb, wkb, wvb, wpb);
  gemm_qkv<<<dim3(24, 32), 256, 0, stream>>>(xb, wqb, wkb, wvb, Qb, Kb, Vb);
  attn_mfma<<<dim3(16, 32), 256, 0, stream>>>(Qb, Kb, Vb, Ab);
  gemm_out64<<<dim3(8, 64), 256, 0, stream>>>(Ab, wpb, bp, out);
}

// Round 6
// 138.415 us; speedup vs baseline: 18.0303x; 1.0657x over previous
//
#include <hip/hip_runtime.h>

#define T_ 2048
#define E_ 1024
#define H_ 16
#define D_ 64
#define M_ 4096   // B*T

typedef unsigned short ushort_t;
typedef __attribute__((ext_vector_type(8))) short bf16x8;
typedef __attribute__((ext_vector_type(4))) float f32x4;
typedef __attribute__((ext_vector_type(4))) unsigned short u16x4;
typedef __attribute__((ext_vector_type(8))) unsigned short u16x8;
typedef __attribute__((ext_vector_type(2))) unsigned int u32x2;

__device__ __forceinline__ ushort_t f2bf(float f) {
  union { float f; unsigned u; } v; v.f = f;
  unsigned r = v.u + 0x7FFFu + ((v.u >> 16) & 1u);
  return (ushort_t)(r >> 16);
}

__device__ __forceinline__ void gl16(const void* g, void* l) {
  __builtin_amdgcn_global_load_lds((const __attribute__((address_space(1))) void*)g,
                                   (__attribute__((address_space(3))) void*)l, 16, 0, 0);
}

// ---------------- all f32->bf16 conversions in ONE launch ----------------
__global__ __launch_bounds__(256)
void conv_all(const float* __restrict__ x,  const float* __restrict__ wq,
              const float* __restrict__ wk, const float* __restrict__ wv,
              const float* __restrict__ wp,
              ushort_t* __restrict__ xb,  ushort_t* __restrict__ wqb,
              ushort_t* __restrict__ wkb, ushort_t* __restrict__ wvb,
              ushort_t* __restrict__ wpb)
{
  const int id = blockIdx.x;
  const float* s; ushort_t* d; size_t off;
  if (id < 2048) { s = x; d = xb; off = (size_t)id * 2048; }
  else {
    int wsel = (id - 2048) >> 9, wid = (id - 2048) & 511;
    off = (size_t)wid * 2048;
    s = wsel == 0 ? wq : wsel == 1 ? wk : wsel == 2 ? wv : wp;
    d = wsel == 0 ? wqb : wsel == 1 ? wkb : wsel == 2 ? wvb : wpb;
  }
  size_t i = off + (size_t)threadIdx.x * 8;
  float4 a = *(const float4*)(s + i);
  float4 b = *(const float4*)(s + i + 4);
  u16x8 o;
  o[0]=f2bf(a.x); o[1]=f2bf(a.y); o[2]=f2bf(a.z); o[3]=f2bf(a.w);
  o[4]=f2bf(b.x); o[5]=f2bf(b.y); o[6]=f2bf(b.z); o[7]=f2bf(b.w);
  *(u16x8*)(d + i) = o;
}

// ---------------- 128x128x(K=1024) bf16 GEMM core, Y = A @ W^T ----------------
__device__ __forceinline__ void gemm_core(const ushort_t* __restrict__ A,
                                          const ushort_t* __restrict__ W,
                                          int m0, int n0,
                                          ushort_t* As, ushort_t* Bs,
                                          f32x4 acc[4][4])
{
  const int t = threadIdx.x;
  const int lane = t & 63, w = t >> 6;
  const int g = lane >> 4, lq = lane & 15;
  const int wr = w >> 1, wc = w & 1;
  const int r0 = t >> 2;
  const int c0 = t & 3;
  const int ca0 = c0 ^ ((r0 >> 1) & 3);
  const int r1 = r0 + 64;
  const int ca1 = c0 ^ ((r1 >> 1) & 3);

  #pragma unroll
  for (int i = 0; i < 4; ++i)
    #pragma unroll
    for (int j = 0; j < 4; ++j) acc[i][j] = (f32x4){0.f,0.f,0.f,0.f};

  for (int k0 = 0; k0 < 1024; k0 += 32) {
    __syncthreads();
    gl16(A + (size_t)(m0 + r0) * 1024 + k0 + ca0 * 8, As + t * 8);
    gl16(A + (size_t)(m0 + r1) * 1024 + k0 + ca1 * 8, As + 2048 + t * 8);
    gl16(W + (size_t)(n0 + r0) * 1024 + k0 + ca0 * 8, Bs + t * 8);
    gl16(W + (size_t)(n0 + r1) * 1024 + k0 + ca1 * 8, Bs + 2048 + t * 8);
    __syncthreads();

    bf16x8 af[4], bfr[4];
    #pragma unroll
    for (int mi = 0; mi < 4; ++mi) {
      int row = wr * 64 + mi * 16 + lq;
      int ch = g ^ ((row >> 1) & 3);
      af[mi] = *(const bf16x8*)(As + row * 32 + ch * 8);
    }
    #pragma unroll
    for (int ni = 0; ni < 4; ++ni) {
      int row = wc * 64 + ni * 16 + lq;
      int ch = g ^ ((row >> 1) & 3);
      bfr[ni] = *(const bf16x8*)(Bs + row * 32 + ch * 8);
    }
    __builtin_amdgcn_s_setprio(1);
    #pragma unroll
    for (int mi = 0; mi < 4; ++mi)
      #pragma unroll
      for (int ni = 0; ni < 4; ++ni)
        acc[mi][ni] = __builtin_amdgcn_mfma_f32_16x16x32_bf16(af[mi], bfr[ni], acc[mi][ni], 0, 0, 0);
    __builtin_amdgcn_s_setprio(0);
  }
}

// Fused QKV projection. grid.x 0..23: sel = x>>3 (Q,K,V), n0 = (x&7)*128.
__global__ __launch_bounds__(256)
void gemm_qkv(const ushort_t* __restrict__ xb,
              const ushort_t* __restrict__ wqb, const ushort_t* __restrict__ wkb,
              const ushort_t* __restrict__ wvb,
              ushort_t* __restrict__ Qd, ushort_t* __restrict__ Kd, ushort_t* __restrict__ Vd)
{
  __shared__ __align__(16) ushort_t As[4096];
  __shared__ __align__(16) ushort_t Bs[4096];
  const int bx = blockIdx.x;
  const int sel = bx >> 3;
  const int n0 = (bx & 7) * 128;
  const int m0 = blockIdx.y * 128;
  const ushort_t* W = sel == 0 ? wqb : (sel == 1 ? wkb : wvb);
  f32x4 acc[4][4];
  gemm_core(xb, W, m0, n0, As, Bs, acc);

  const int t = threadIdx.x, lane = t & 63, w = t >> 6;
  const int g = lane >> 4, lq = lane & 15, wr = w >> 1, wc = w & 1;
  const float scl = (sel == 0) ? 0.125f : 1.0f;
  ushort_t* dst = sel == 0 ? Qd : (sel == 1 ? Kd : Vd);
  #pragma unroll
  for (int mi = 0; mi < 4; ++mi)
    #pragma unroll
    for (int ni = 0; ni < 4; ++ni)
      #pragma unroll
      for (int r = 0; r < 4; ++r) {
        int m = m0 + wr * 64 + mi * 16 + 4 * g + r;
        int n = n0 + wc * 64 + ni * 16 + lq;
        int b = m >> 11, tt = m & (T_ - 1);
        int h = n >> 6, d = n & (D_ - 1);
        ushort_t v = f2bf(acc[mi][ni][r] * scl);
        if (sel < 2) dst[((size_t)(b * H_ + h) * T_ + tt) * D_ + d] = v;
        else         dst[((size_t)(b * H_ + h) * D_ + d) * T_ + tt] = v;
      }
}

// Output projection, 64x128 tiles: out = Ab @ Wp^T + bp (fp32). grid (8, 64).
__global__ __launch_bounds__(256)
void gemm_out64(const ushort_t* __restrict__ Ab, const ushort_t* __restrict__ wpb,
                const float* __restrict__ bias, float* __restrict__ out)
{
  __shared__ __align__(16) ushort_t As[2048];   // 64 x 32
  __shared__ __align__(16) ushort_t Bs[4096];   // 128 x 32
  const int t = threadIdx.x, lane = t & 63, w = t >> 6;
  const int g = lane >> 4, lq = lane & 15;
  const int n0 = blockIdx.x * 128;
  const int m0 = blockIdx.y * 64;
  const int r0 = t >> 2, c0 = t & 3;
  const int ca0 = c0 ^ ((r0 >> 1) & 3);
  const int r1 = r0 + 64;
  const int ca1 = c0 ^ ((r1 >> 1) & 3);

  f32x4 acc[4][2];
  #pragma unroll
  for (int i = 0; i < 4; ++i) { acc[i][0] = (f32x4){0.f,0.f,0.f,0.f}; acc[i][1] = (f32x4){0.f,0.f,0.f,0.f}; }

  for (int k0 = 0; k0 < 1024; k0 += 32) {
    __syncthreads();
    gl16(Ab  + (size_t)(m0 + r0) * 1024 + k0 + ca0 * 8, As + t * 8);
    gl16(wpb + (size_t)(n0 + r0) * 1024 + k0 + ca0 * 8, Bs + t * 8);
    gl16(wpb + (size_t)(n0 + r1) * 1024 + k0 + ca1 * 8, Bs + 2048 + t * 8);
    __syncthreads();

    bf16x8 af[4], bfr[2];
    #pragma unroll
    for (int mi = 0; mi < 4; ++mi) {
      int row = mi * 16 + lq;
      int ch = g ^ ((row >> 1) & 3);
      af[mi] = *(const bf16x8*)(As + row * 32 + ch * 8);
    }
    #pragma unroll
    for (int ni = 0; ni < 2; ++ni) {
      int row = w * 32 + ni * 16 + lq;
      int ch = g ^ ((row >> 1) & 3);
      bfr[ni] = *(const bf16x8*)(Bs + row * 32 + ch * 8);
    }
    __builtin_amdgcn_s_setprio(1);
    #pragma unroll
    for (int mi = 0; mi < 4; ++mi)
      #pragma unroll
      for (int ni = 0; ni < 2; ++ni)
        acc[mi][ni] = __builtin_amdgcn_mfma_f32_16x16x32_bf16(af[mi], bfr[ni], acc[mi][ni], 0, 0, 0);
    __builtin_amdgcn_s_setprio(0);
  }
  #pragma unroll
  for (int mi = 0; mi < 4; ++mi)
    #pragma unroll
    for (int ni = 0; ni < 2; ++ni)
      #pragma unroll
      for (int r = 0; r < 4; ++r) {
        int m = m0 + mi * 16 + 4 * g + r;
        int n = n0 + w * 32 + ni * 16 + lq;
        out[(size_t)m * E_ + n] = acc[mi][ni][r] + bias[n];
      }
}

// ---------------- MFMA flash attention v3 ----------------
// QBLK=128 (4 waves x 32 q-rows), KVBLK=64, double-buffered K/V, Q in regs.
// v3: cvt_pk P-packing, defer-max rescale (THR=8), PV loop pure-MFMA.
__global__ __launch_bounds__(256)
void attn_mfma(const ushort_t* __restrict__ Q, const ushort_t* __restrict__ K,
               const ushort_t* __restrict__ Vt, ushort_t* __restrict__ O)
{
  __shared__ __align__(16) ushort_t Ks[2][4096];
  __shared__ __align__(16) ushort_t Vs[2][4096];
  __shared__ __align__(16) ushort_t Ps[128 * 72];
  const int t = threadIdx.x, w = t >> 6, lane = t & 63;
  const int g = lane >> 4, lq = lane & 15;
  const int bh = blockIdx.y;
  const int qt = 15 - ((blockIdx.x + bh) & 15);   // balance: mix tile sizes per CU, big first
  const int q0 = qt * 128;
  const size_t qkbase = (size_t)bh * T_ * D_;
  const size_t vbase  = (size_t)bh * D_ * T_;

  const int srow = t >> 3, sc = t & 7;
  const int cs0 = sc ^ (srow & 7);
  const int srow1 = srow + 32;
  const int cs1 = sc ^ (srow1 & 7);

  // Q fragments directly to registers (read once; no LDS, no barrier)
  const int rowA = 32 * w + lq, rowB = rowA + 16;
  const int qgA = q0 + rowA, qgB = q0 + rowB;
  const bf16x8 qA0 = *(const bf16x8*)(Q + qkbase + (size_t)qgA * D_ + g * 8);
  const bf16x8 qA1 = *(const bf16x8*)(Q + qkbase + (size_t)qgA * D_ + 32 + g * 8);
  const bf16x8 qB0 = *(const bf16x8*)(Q + qkbase + (size_t)qgB * D_ + g * 8);
  const bf16x8 qB1 = *(const bf16x8*)(Q + qkbase + (size_t)qgB * D_ + 32 + g * 8);

  f32x4 accA[4], accB[4];
  #pragma unroll
  for (int db = 0; db < 4; ++db) { accA[db] = (f32x4){0.f,0.f,0.f,0.f}; accB[db] = (f32x4){0.f,0.f,0.f,0.f}; }
  float mA = -1e30f, lA = 0.f, mB = -1e30f, lB = 0.f;

  const int nt = 2 * qt + 2;

  // prologue: stage tile 0 into buf 0
  {
    gl16(K + qkbase + (size_t)srow  * D_ + cs0 * 8, &Ks[0][t * 8]);
    gl16(K + qkbase + (size_t)srow1 * D_ + cs1 * 8, &Ks[0][2048 + t * 8]);
    gl16(Vt + vbase + (size_t)srow  * T_ + cs0 * 8, &Vs[0][t * 8]);
    gl16(Vt + vbase + (size_t)srow1 * T_ + cs1 * 8, &Vs[0][2048 + t * 8]);
  }
  __syncthreads();

  for (int kt = 0; kt < nt; ++kt) {
    const int cur = kt & 1;
    const int k0 = kt * 64;
    if (kt + 1 < nt) {                       // prefetch next tile into other buffer
      const int kn = (kt + 1) * 64;
      gl16(K + qkbase + (size_t)(kn + srow)  * D_ + cs0 * 8, &Ks[cur ^ 1][t * 8]);
      gl16(K + qkbase + (size_t)(kn + srow1) * D_ + cs1 * 8, &Ks[cur ^ 1][2048 + t * 8]);
      gl16(Vt + vbase + (size_t)srow  * T_ + kn + cs0 * 8, &Vs[cur ^ 1][t * 8]);
      gl16(Vt + vbase + (size_t)srow1 * T_ + kn + cs1 * 8, &Vs[cur ^ 1][2048 + t * 8]);
    }
    const ushort_t* kb_ = &Ks[cur][0];
    const ushort_t* vb_ = &Vs[cur][0];

    // S^T = K . Q^T (each K fragment feeds both q sub-blocks)
    f32x4 stA[4], stB[4];
    __builtin_amdgcn_s_setprio(1);
    #pragma unroll
    for (int kb = 0; kb < 4; ++kb) {
      int krow = kb * 16 + lq;
      bf16x8 ka0 = *(const bf16x8*)(kb_ + krow * 64 + ((g ^ (krow & 7)) * 8));
      bf16x8 ka1 = *(const bf16x8*)(kb_ + krow * 64 + (((4 + g) ^ (krow & 7)) * 8));
      f32x4 zA = (f32x4){0.f,0.f,0.f,0.f};
      zA = __builtin_amdgcn_mfma_f32_16x16x32_bf16(ka0, qA0, zA, 0, 0, 0);
      zA = __builtin_amdgcn_mfma_f32_16x16x32_bf16(ka1, qA1, zA, 0, 0, 0);
      stA[kb] = zA;
      f32x4 zB = (f32x4){0.f,0.f,0.f,0.f};
      zB = __builtin_amdgcn_mfma_f32_16x16x32_bf16(ka0, qB0, zB, 0, 0, 0);
      zB = __builtin_amdgcn_mfma_f32_16x16x32_bf16(ka1, qB1, zB, 0, 0, 0);
      stB[kb] = zB;
    }
    __builtin_amdgcn_s_setprio(0);

    if (kt >= nt - 2) {                      // only diagonal-adjacent tiles mask
      #pragma unroll
      for (int kb = 0; kb < 4; ++kb)
        #pragma unroll
        for (int r = 0; r < 4; ++r) {
          int kg = k0 + kb * 16 + 4 * g + r;
          if (kg > qgA) stA[kb][r] = -1e30f;
          if (kg > qgB) stB[kb][r] = -1e30f;
        }
    }

    float tmA = -1e30f, tmB = -1e30f;
    #pragma unroll
    for (int kb = 0; kb < 4; ++kb)
      #pragma unroll
      for (int r = 0; r < 4; ++r) { tmA = fmaxf(tmA, stA[kb][r]); tmB = fmaxf(tmB, stB[kb][r]); }
    tmA = fmaxf(tmA, __shfl_xor(tmA, 16)); tmA = fmaxf(tmA, __shfl_xor(tmA, 32));
    tmB = fmaxf(tmB, __shfl_xor(tmB, 16)); tmB = fmaxf(tmB, __shfl_xor(tmB, 32));

    // defer-max: only rescale when a row's max grew by > 8 (wave-uniform branch)
    if (!__all((tmA <= mA + 8.f) && (tmB <= mB + 8.f))) {
      float mnA = fmaxf(mA, tmA), mnB = fmaxf(mB, tmB);
      float alA = __expf(mA - mnA), alB = __expf(mB - mnB);
      mA = mnA; mB = mnB;
      lA *= alA; lB *= alB;
      float alAr[4], alBr[4];
      #pragma unroll
      for (int r = 0; r < 4; ++r) { alAr[r] = __shfl(alA, 4 * g + r); alBr[r] = __shfl(alB, 4 * g + r); }
      #pragma unroll
      for (int db = 0; db < 4; ++db)
        #pragma unroll
        for (int r = 0; r < 4; ++r) { accA[db][r] *= alAr[r]; accB[db][r] *= alBr[r]; }
    }

    float tsA = 0.f, tsB = 0.f;
    #pragma unroll
    for (int kb = 0; kb < 4; ++kb) {
      float pA0 = __expf(stA[kb][0] - mA), pA1 = __expf(stA[kb][1] - mA);
      float pA2 = __expf(stA[kb][2] - mA), pA3 = __expf(stA[kb][3] - mA);
      float pB0 = __expf(stB[kb][0] - mB), pB1 = __expf(stB[kb][1] - mB);
      float pB2 = __expf(stB[kb][2] - mB), pB3 = __expf(stB[kb][3] - mB);
      tsA += (pA0 + pA1) + (pA2 + pA3);
      tsB += (pB0 + pB1) + (pB2 + pB3);
      unsigned aLo, aHi, bLo, bHi;
      asm("v_cvt_pk_bf16_f32 %0, %1, %2" : "=v"(aLo) : "v"(pA0), "v"(pA1));
      asm("v_cvt_pk_bf16_f32 %0, %1, %2" : "=v"(aHi) : "v"(pA2), "v"(pA3));
      asm("v_cvt_pk_bf16_f32 %0, %1, %2" : "=v"(bLo) : "v"(pB0), "v"(pB1));
      asm("v_cvt_pk_bf16_f32 %0, %1, %2" : "=v"(bHi) : "v"(pB2), "v"(pB3));
      *(u32x2*)(Ps + rowA * 72 + kb * 16 + 4 * g) = (u32x2){aLo, aHi};
      *(u32x2*)(Ps + rowB * 72 + kb * 16 + 4 * g) = (u32x2){bLo, bHi};
    }
    tsA += __shfl_xor(tsA, 16); tsA += __shfl_xor(tsA, 32);
    tsB += __shfl_xor(tsB, 16); tsB += __shfl_xor(tsB, 32);
    lA += tsA; lB += tsB;

    asm volatile("s_waitcnt lgkmcnt(0)" ::: "memory");   // own-wave Ps writes visible
    bf16x8 paA0 = *(const bf16x8*)(Ps + rowA * 72 + g * 8);
    bf16x8 paA1 = *(const bf16x8*)(Ps + rowA * 72 + 32 + g * 8);
    bf16x8 paB0 = *(const bf16x8*)(Ps + rowB * 72 + g * 8);
    bf16x8 paB1 = *(const bf16x8*)(Ps + rowB * 72 + 32 + g * 8);

    __builtin_amdgcn_s_setprio(1);
    #pragma unroll
    for (int db = 0; db < 4; ++db) {
      int vrow = db * 16 + lq;
      bf16x8 vb0 = *(const bf16x8*)(vb_ + vrow * 64 + ((g ^ (vrow & 7)) * 8));
      bf16x8 vb1 = *(const bf16x8*)(vb_ + vrow * 64 + (((4 + g) ^ (vrow & 7)) * 8));
      accA[db] = __builtin_amdgcn_mfma_f32_16x16x32_bf16(paA0, vb0, accA[db], 0, 0, 0);
      accA[db] = __builtin_amdgcn_mfma_f32_16x16x32_bf16(paA1, vb1, accA[db], 0, 0, 0);
      accB[db] = __builtin_amdgcn_mfma_f32_16x16x32_bf16(paB0, vb0, accB[db], 0, 0, 0);
      accB[db] = __builtin_amdgcn_mfma_f32_16x16x32_bf16(paB1, vb1, accB[db], 0, 0, 0);
    }
    __builtin_amdgcn_s_setprio(0);

    __syncthreads();   // drains prefetch vmcnt + all LDS reads before buffer reuse
  }

  float invA = 1.0f / lA, invB = 1.0f / lB;
  float liA[4], liB[4];
  #pragma unroll
  for (int r = 0; r < 4; ++r) { liA[r] = __shfl(invA, 4 * g + r); liB[r] = __shfl(invB, 4 * g + r); }
  const int b = bh >> 4, h = bh & 15;
  #pragma unroll
  for (int db = 0; db < 4; ++db)
    #pragma unroll
    for (int r = 0; r < 4; ++r) {
      int mAo = q0 + 32 * w + 4 * g + r;
      int mBo = mAo + 16;
      O[((size_t)(b * T_ + mAo)) * E_ + h * 64 + db * 16 + lq] = f2bf(accA[db][r] * liA[r]);
      O[((size_t)(b * T_ + mBo)) * E_ + h * 64 + db * 16 + lq] = f2bf(accB[db][r] * liB[r]);
    }
}

extern "C" void kernel_launch(void* const* d_in, const int* in_sizes, int n_in,
                              void* d_out, int out_size, void* d_ws, size_t ws_size,
                              hipStream_t stream) {
  const float* x  = (const float*)d_in[0];
  const float* Wq = (const float*)d_in[1];
  const float* Wk = (const float*)d_in[2];
  const float* Wv = (const float*)d_in[3];
  const float* Wp = (const float*)d_in[4];
  const float* bp = (const float*)d_in[5];
  float* out = (float*)d_out;

  ushort_t* ws  = (ushort_t*)d_ws;
  ushort_t* xb  = ws;
  ushort_t* wqb = xb  + (size_t)M_ * E_;
  ushort_t* wkb = wqb + (size_t)E_ * E_;
  ushort_t* wvb = wkb + (size_t)E_ * E_;
  ushort_t* wpb = wvb + (size_t)E_ * E_;
  ushort_t* Qb  = wpb + (size_t)E_ * E_;
  ushort_t* Kb  = Qb  + (size_t)M_ * E_;
  ushort_t* Vb  = Kb  + (size_t)M_ * E_;
  ushort_t* Ab  = Vb  + (size_t)M_ * E_;

  conv_all<<<4096, 256, 0, stream>>>(x, Wq, Wk, Wv, Wp, xb, wqb, wkb, wvb, wpb);
  gemm_qkv<<<dim3(24, 32), 256, 0, stream>>>(xb, wqb, wkb, wvb, Qb, Kb, Vb);
  attn_mfma<<<dim3(16, 32), 256, 0, stream>>>(Qb, Kb, Vb, Ab);
  gemm_out64<<<dim3(8, 64), 256, 0, stream>>>(Ab, wpb, bp, out);
}

// Round 7
// 137.109 us; speedup vs baseline: 18.2019x; 1.0095x over previous
//
#include <hip/hip_runtime.h>

#define T_ 2048
#define E_ 1024
#define H_ 16
#define D_ 64
#define M_ 4096   // B*T

typedef unsigned short ushort_t;
typedef __attribute__((ext_vector_type(8))) short bf16x8;
typedef __attribute__((ext_vector_type(4))) float f32x4;
typedef __attribute__((ext_vector_type(4))) unsigned short u16x4;
typedef __attribute__((ext_vector_type(8))) unsigned short u16x8;
typedef __attribute__((ext_vector_type(2))) unsigned int u32x2;

__device__ __forceinline__ ushort_t f2bf(float f) {
  union { float f; unsigned u; } v; v.f = f;
  unsigned r = v.u + 0x7FFFu + ((v.u >> 16) & 1u);
  return (ushort_t)(r >> 16);
}

__device__ __forceinline__ void gl16(const void* g, void* l) {
  __builtin_amdgcn_global_load_lds((const __attribute__((address_space(1))) void*)g,
                                   (__attribute__((address_space(3))) void*)l, 16, 0, 0);
}

// ---------------- all f32->bf16 conversions in ONE launch ----------------
__global__ __launch_bounds__(256)
void conv_all(const float* __restrict__ x,  const float* __restrict__ wq,
              const float* __restrict__ wk, const float* __restrict__ wv,
              const float* __restrict__ wp,
              ushort_t* __restrict__ xb,  ushort_t* __restrict__ wqb,
              ushort_t* __restrict__ wkb, ushort_t* __restrict__ wvb,
              ushort_t* __restrict__ wpb)
{
  const int id = blockIdx.x;
  const float* s; ushort_t* d; size_t off;
  if (id < 2048) { s = x; d = xb; off = (size_t)id * 2048; }
  else {
    int wsel = (id - 2048) >> 9, wid = (id - 2048) & 511;
    off = (size_t)wid * 2048;
    s = wsel == 0 ? wq : wsel == 1 ? wk : wsel == 2 ? wv : wp;
    d = wsel == 0 ? wqb : wsel == 1 ? wkb : wsel == 2 ? wvb : wpb;
  }
  size_t i = off + (size_t)threadIdx.x * 8;
  float4 a = *(const float4*)(s + i);
  float4 b = *(const float4*)(s + i + 4);
  u16x8 o;
  o[0]=f2bf(a.x); o[1]=f2bf(a.y); o[2]=f2bf(a.z); o[3]=f2bf(a.w);
  o[4]=f2bf(b.x); o[5]=f2bf(b.y); o[6]=f2bf(b.z); o[7]=f2bf(b.w);
  *(u16x8*)(d + i) = o;
}

// ---------------- 128x128x(K=1024) bf16 GEMM core, Y = A @ W^T ----------------
__device__ __forceinline__ void gemm_core(const ushort_t* __restrict__ A,
                                          const ushort_t* __restrict__ W,
                                          int m0, int n0,
                                          ushort_t* As, ushort_t* Bs,
                                          f32x4 acc[4][4])
{
  const int t = threadIdx.x;
  const int lane = t & 63, w = t >> 6;
  const int g = lane >> 4, lq = lane & 15;
  const int wr = w >> 1, wc = w & 1;
  const int r0 = t >> 2;
  const int c0 = t & 3;
  const int ca0 = c0 ^ ((r0 >> 1) & 3);
  const int r1 = r0 + 64;
  const int ca1 = c0 ^ ((r1 >> 1) & 3);

  #pragma unroll
  for (int i = 0; i < 4; ++i)
    #pragma unroll
    for (int j = 0; j < 4; ++j) acc[i][j] = (f32x4){0.f,0.f,0.f,0.f};

  for (int k0 = 0; k0 < 1024; k0 += 32) {
    __syncthreads();
    gl16(A + (size_t)(m0 + r0) * 1024 + k0 + ca0 * 8, As + t * 8);
    gl16(A + (size_t)(m0 + r1) * 1024 + k0 + ca1 * 8, As + 2048 + t * 8);
    gl16(W + (size_t)(n0 + r0) * 1024 + k0 + ca0 * 8, Bs + t * 8);
    gl16(W + (size_t)(n0 + r1) * 1024 + k0 + ca1 * 8, Bs + 2048 + t * 8);
    __syncthreads();

    bf16x8 af[4], bfr[4];
    #pragma unroll
    for (int mi = 0; mi < 4; ++mi) {
      int row = wr * 64 + mi * 16 + lq;
      int ch = g ^ ((row >> 1) & 3);
      af[mi] = *(const bf16x8*)(As + row * 32 + ch * 8);
    }
    #pragma unroll
    for (int ni = 0; ni < 4; ++ni) {
      int row = wc * 64 + ni * 16 + lq;
      int ch = g ^ ((row >> 1) & 3);
      bfr[ni] = *(const bf16x8*)(Bs + row * 32 + ch * 8);
    }
    __builtin_amdgcn_s_setprio(1);
    #pragma unroll
    for (int mi = 0; mi < 4; ++mi)
      #pragma unroll
      for (int ni = 0; ni < 4; ++ni)
        acc[mi][ni] = __builtin_amdgcn_mfma_f32_16x16x32_bf16(af[mi], bfr[ni], acc[mi][ni], 0, 0, 0);
    __builtin_amdgcn_s_setprio(0);
  }
}

// Fused QKV projection. grid.x 0..23: sel = x>>3 (Q,K,V), n0 = (x&7)*128.
__global__ __launch_bounds__(256)
void gemm_qkv(const ushort_t* __restrict__ xb,
              const ushort_t* __restrict__ wqb, const ushort_t* __restrict__ wkb,
              const ushort_t* __restrict__ wvb,
              ushort_t* __restrict__ Qd, ushort_t* __restrict__ Kd, ushort_t* __restrict__ Vd)
{
  __shared__ __align__(16) ushort_t As[4096];
  __shared__ __align__(16) ushort_t Bs[4096];
  const int bx = blockIdx.x;
  const int sel = bx >> 3;
  const int n0 = (bx & 7) * 128;
  const int m0 = blockIdx.y * 128;
  const ushort_t* W = sel == 0 ? wqb : (sel == 1 ? wkb : wvb);
  f32x4 acc[4][4];
  gemm_core(xb, W, m0, n0, As, Bs, acc);

  const int t = threadIdx.x, lane = t & 63, w = t >> 6;
  const int g = lane >> 4, lq = lane & 15, wr = w >> 1, wc = w & 1;
  const float scl = (sel == 0) ? 0.125f : 1.0f;
  ushort_t* dst = sel == 0 ? Qd : (sel == 1 ? Kd : Vd);
  #pragma unroll
  for (int mi = 0; mi < 4; ++mi)
    #pragma unroll
    for (int ni = 0; ni < 4; ++ni)
      #pragma unroll
      for (int r = 0; r < 4; ++r) {
        int m = m0 + wr * 64 + mi * 16 + 4 * g + r;
        int n = n0 + wc * 64 + ni * 16 + lq;
        int b = m >> 11, tt = m & (T_ - 1);
        int h = n >> 6, d = n & (D_ - 1);
        ushort_t v = f2bf(acc[mi][ni][r] * scl);
        if (sel < 2) dst[((size_t)(b * H_ + h) * T_ + tt) * D_ + d] = v;
        else         dst[((size_t)(b * H_ + h) * D_ + d) * T_ + tt] = v;
      }
}

// Output projection, 64x128 tiles: out = Ab @ Wp^T + bp (fp32). grid (8, 64).
__global__ __launch_bounds__(256)
void gemm_out64(const ushort_t* __restrict__ Ab, const ushort_t* __restrict__ wpb,
                const float* __restrict__ bias, float* __restrict__ out)
{
  __shared__ __align__(16) ushort_t As[2048];   // 64 x 32
  __shared__ __align__(16) ushort_t Bs[4096];   // 128 x 32
  const int t = threadIdx.x, lane = t & 63, w = t >> 6;
  const int g = lane >> 4, lq = lane & 15;
  const int n0 = blockIdx.x * 128;
  const int m0 = blockIdx.y * 64;
  const int r0 = t >> 2, c0 = t & 3;
  const int ca0 = c0 ^ ((r0 >> 1) & 3);
  const int r1 = r0 + 64;
  const int ca1 = c0 ^ ((r1 >> 1) & 3);

  f32x4 acc[4][2];
  #pragma unroll
  for (int i = 0; i < 4; ++i) { acc[i][0] = (f32x4){0.f,0.f,0.f,0.f}; acc[i][1] = (f32x4){0.f,0.f,0.f,0.f}; }

  for (int k0 = 0; k0 < 1024; k0 += 32) {
    __syncthreads();
    gl16(Ab  + (size_t)(m0 + r0) * 1024 + k0 + ca0 * 8, As + t * 8);
    gl16(wpb + (size_t)(n0 + r0) * 1024 + k0 + ca0 * 8, Bs + t * 8);
    gl16(wpb + (size_t)(n0 + r1) * 1024 + k0 + ca1 * 8, Bs + 2048 + t * 8);
    __syncthreads();

    bf16x8 af[4], bfr[2];
    #pragma unroll
    for (int mi = 0; mi < 4; ++mi) {
      int row = mi * 16 + lq;
      int ch = g ^ ((row >> 1) & 3);
      af[mi] = *(const bf16x8*)(As + row * 32 + ch * 8);
    }
    #pragma unroll
    for (int ni = 0; ni < 2; ++ni) {
      int row = w * 32 + ni * 16 + lq;
      int ch = g ^ ((row >> 1) & 3);
      bfr[ni] = *(const bf16x8*)(Bs + row * 32 + ch * 8);
    }
    __builtin_amdgcn_s_setprio(1);
    #pragma unroll
    for (int mi = 0; mi < 4; ++mi)
      #pragma unroll
      for (int ni = 0; ni < 2; ++ni)
        acc[mi][ni] = __builtin_amdgcn_mfma_f32_16x16x32_bf16(af[mi], bfr[ni], acc[mi][ni], 0, 0, 0);
    __builtin_amdgcn_s_setprio(0);
  }
  #pragma unroll
  for (int mi = 0; mi < 4; ++mi)
    #pragma unroll
    for (int ni = 0; ni < 2; ++ni)
      #pragma unroll
      for (int r = 0; r < 4; ++r) {
        int m = m0 + mi * 16 + 4 * g + r;
        int n = n0 + w * 32 + ni * 16 + lq;
        out[(size_t)m * E_ + n] = acc[mi][ni][r] + bias[n];
      }
}

// ---------------- MFMA flash attention v4: barrier-free, K/V direct from L1/L2 ----------------
// QBLK=128 (4 waves x 32 q-rows). NO K/V LDS staging; LDS holds only per-wave Ps.
// Grid 512 linear; XCD-aware placement: xcd = i&7 owns heads 4x..4x+3; complementary
// qt pairing (chunks c and c+32 -> qt and 15-qt) => uniform 34 steps/CU.
__global__ __launch_bounds__(256, 2)
void attn_mfma(const ushort_t* __restrict__ Q, const ushort_t* __restrict__ K,
               const ushort_t* __restrict__ Vt, ushort_t* __restrict__ O)
{
  __shared__ __align__(16) ushort_t Ps[128 * 72];
  const int t = threadIdx.x, w = t >> 6, lane = t & 63;
  const int g = lane >> 4, lq = lane & 15;
  const int i = blockIdx.x;
  const int xcd = i & 7, chunk = i >> 3;
  const int bh = xcd * 4 + (chunk >> 4);
  const int qt = (chunk < 32) ? (chunk & 15) : (15 - (chunk & 15));
  const int q0 = qt * 128;
  const size_t qkbase = (size_t)bh * T_ * D_;
  const size_t vbase  = (size_t)bh * D_ * T_;

  // Q fragments directly to registers (read once)
  const int rowA = 32 * w + lq, rowB = rowA + 16;
  const int qgA = q0 + rowA, qgB = q0 + rowB;
  const bf16x8 qA0 = *(const bf16x8*)(Q + qkbase + (size_t)qgA * D_ + g * 8);
  const bf16x8 qA1 = *(const bf16x8*)(Q + qkbase + (size_t)qgA * D_ + 32 + g * 8);
  const bf16x8 qB0 = *(const bf16x8*)(Q + qkbase + (size_t)qgB * D_ + g * 8);
  const bf16x8 qB1 = *(const bf16x8*)(Q + qkbase + (size_t)qgB * D_ + 32 + g * 8);

  f32x4 accA[4], accB[4];
  #pragma unroll
  for (int db = 0; db < 4; ++db) { accA[db] = (f32x4){0.f,0.f,0.f,0.f}; accB[db] = (f32x4){0.f,0.f,0.f,0.f}; }
  float mA = -1e30f, lA = 0.f, mB = -1e30f, lB = 0.f;

  const int nt = 2 * qt + 2;

  for (int kt = 0; kt < nt; ++kt) {
    const int k0 = kt * 64;

    // issue ALL K and V fragment loads up front (L1/L2-resident; latency hides under QK+softmax)
    bf16x8 kf0[4], kf1[4], vf0[4], vf1[4];
    #pragma unroll
    for (int kb = 0; kb < 4; ++kb) {
      const ushort_t* kp = K + qkbase + (size_t)(k0 + kb * 16 + lq) * D_;
      kf0[kb] = *(const bf16x8*)(kp + g * 8);
      kf1[kb] = *(const bf16x8*)(kp + 32 + g * 8);
    }
    #pragma unroll
    for (int db = 0; db < 4; ++db) {
      const ushort_t* vp = Vt + vbase + (size_t)(db * 16 + lq) * T_ + k0;
      vf0[db] = *(const bf16x8*)(vp + g * 8);
      vf1[db] = *(const bf16x8*)(vp + 32 + g * 8);
    }

    // S^T = K . Q^T (each K fragment feeds both q sub-blocks)
    f32x4 stA[4], stB[4];
    __builtin_amdgcn_s_setprio(1);
    #pragma unroll
    for (int kb = 0; kb < 4; ++kb) {
      f32x4 zA = (f32x4){0.f,0.f,0.f,0.f};
      zA = __builtin_amdgcn_mfma_f32_16x16x32_bf16(kf0[kb], qA0, zA, 0, 0, 0);
      zA = __builtin_amdgcn_mfma_f32_16x16x32_bf16(kf1[kb], qA1, zA, 0, 0, 0);
      stA[kb] = zA;
      f32x4 zB = (f32x4){0.f,0.f,0.f,0.f};
      zB = __builtin_amdgcn_mfma_f32_16x16x32_bf16(kf0[kb], qB0, zB, 0, 0, 0);
      zB = __builtin_amdgcn_mfma_f32_16x16x32_bf16(kf1[kb], qB1, zB, 0, 0, 0);
      stB[kb] = zB;
    }
    __builtin_amdgcn_s_setprio(0);

    if (kt >= nt - 2) {                      // only diagonal-adjacent tiles mask
      #pragma unroll
      for (int kb = 0; kb < 4; ++kb)
        #pragma unroll
        for (int r = 0; r < 4; ++r) {
          int kg = k0 + kb * 16 + 4 * g + r;
          if (kg > qgA) stA[kb][r] = -1e30f;
          if (kg > qgB) stB[kb][r] = -1e30f;
        }
    }

    float tmA = -1e30f, tmB = -1e30f;
    #pragma unroll
    for (int kb = 0; kb < 4; ++kb)
      #pragma unroll
      for (int r = 0; r < 4; ++r) { tmA = fmaxf(tmA, stA[kb][r]); tmB = fmaxf(tmB, stB[kb][r]); }
    tmA = fmaxf(tmA, __shfl_xor(tmA, 16)); tmA = fmaxf(tmA, __shfl_xor(tmA, 32));
    tmB = fmaxf(tmB, __shfl_xor(tmB, 16)); tmB = fmaxf(tmB, __shfl_xor(tmB, 32));

    // defer-max: only rescale when a row's max grew by > 8 (wave-uniform branch)
    if (!__all((tmA <= mA + 8.f) && (tmB <= mB + 8.f))) {
      float mnA = fmaxf(mA, tmA), mnB = fmaxf(mB, tmB);
      float alA = __expf(mA - mnA), alB = __expf(mB - mnB);
      mA = mnA; mB = mnB;
      lA *= alA; lB *= alB;
      float alAr[4], alBr[4];
      #pragma unroll
      for (int r = 0; r < 4; ++r) { alAr[r] = __shfl(alA, 4 * g + r); alBr[r] = __shfl(alB, 4 * g + r); }
      #pragma unroll
      for (int db = 0; db < 4; ++db)
        #pragma unroll
        for (int r = 0; r < 4; ++r) { accA[db][r] *= alAr[r]; accB[db][r] *= alBr[r]; }
    }

    float tsA = 0.f, tsB = 0.f;
    #pragma unroll
    for (int kb = 0; kb < 4; ++kb) {
      float pA0 = __expf(stA[kb][0] - mA), pA1 = __expf(stA[kb][1] - mA);
      float pA2 = __expf(stA[kb][2] - mA), pA3 = __expf(stA[kb][3] - mA);
      float pB0 = __expf(stB[kb][0] - mB), pB1 = __expf(stB[kb][1] - mB);
      float pB2 = __expf(stB[kb][2] - mB), pB3 = __expf(stB[kb][3] - mB);
      tsA += (pA0 + pA1) + (pA2 + pA3);
      tsB += (pB0 + pB1) + (pB2 + pB3);
      unsigned aLo, aHi, bLo, bHi;
      asm("v_cvt_pk_bf16_f32 %0, %1, %2" : "=v"(aLo) : "v"(pA0), "v"(pA1));
      asm("v_cvt_pk_bf16_f32 %0, %1, %2" : "=v"(aHi) : "v"(pA2), "v"(pA3));
      asm("v_cvt_pk_bf16_f32 %0, %1, %2" : "=v"(bLo) : "v"(pB0), "v"(pB1));
      asm("v_cvt_pk_bf16_f32 %0, %1, %2" : "=v"(bHi) : "v"(pB2), "v"(pB3));
      *(u32x2*)(Ps + rowA * 72 + kb * 16 + 4 * g) = (u32x2){aLo, aHi};
      *(u32x2*)(Ps + rowB * 72 + kb * 16 + 4 * g) = (u32x2){bLo, bHi};
    }
    tsA += __shfl_xor(tsA, 16); tsA += __shfl_xor(tsA, 32);
    tsB += __shfl_xor(tsB, 16); tsB += __shfl_xor(tsB, 32);
    lA += tsA; lB += tsB;

    asm volatile("s_waitcnt lgkmcnt(0)" ::: "memory");   // own-wave Ps writes visible
    bf16x8 paA0 = *(const bf16x8*)(Ps + rowA * 72 + g * 8);
    bf16x8 paA1 = *(const bf16x8*)(Ps + rowA * 72 + 32 + g * 8);
    bf16x8 paB0 = *(const bf16x8*)(Ps + rowB * 72 + g * 8);
    bf16x8 paB1 = *(const bf16x8*)(Ps + rowB * 72 + 32 + g * 8);

    __builtin_amdgcn_s_setprio(1);
    #pragma unroll
    for (int db = 0; db < 4; ++db) {
      accA[db] = __builtin_amdgcn_mfma_f32_16x16x32_bf16(paA0, vf0[db], accA[db], 0, 0, 0);
      accA[db] = __builtin_amdgcn_mfma_f32_16x16x32_bf16(paA1, vf1[db], accA[db], 0, 0, 0);
      accB[db] = __builtin_amdgcn_mfma_f32_16x16x32_bf16(paB0, vf0[db], accB[db], 0, 0, 0);
      accB[db] = __builtin_amdgcn_mfma_f32_16x16x32_bf16(paB1, vf1[db], accB[db], 0, 0, 0);
    }
    __builtin_amdgcn_s_setprio(0);
  }

  float invA = 1.0f / lA, invB = 1.0f / lB;
  float liA[4], liB[4];
  #pragma unroll
  for (int r = 0; r < 4; ++r) { liA[r] = __shfl(invA, 4 * g + r); liB[r] = __shfl(invB, 4 * g + r); }
  const int b = bh >> 4, h = bh & 15;
  #pragma unroll
  for (int db = 0; db < 4; ++db)
    #pragma unroll
    for (int r = 0; r < 4; ++r) {
      int mAo = q0 + 32 * w + 4 * g + r;
      int mBo = mAo + 16;
      O[((size_t)(b * T_ + mAo)) * E_ + h * 64 + db * 16 + lq] = f2bf(accA[db][r] * liA[r]);
      O[((size_t)(b * T_ + mBo)) * E_ + h * 64 + db * 16 + lq] = f2bf(accB[db][r] * liB[r]);
    }
}

extern "C" void kernel_launch(void* const* d_in, const int* in_sizes, int n_in,
                              void* d_out, int out_size, void* d_ws, size_t ws_size,
                              hipStream_t stream) {
  const float* x  = (const float*)d_in[0];
  const float* Wq = (const float*)d_in[1];
  const float* Wk = (const float*)d_in[2];
  const float* Wv = (const float*)d_in[3];
  const float* Wp = (const float*)d_in[4];
  const float* bp = (const float*)d_in[5];
  float* out = (float*)d_out;

  ushort_t* ws  = (ushort_t*)d_ws;
  ushort_t* xb  = ws;
  ushort_t* wqb = xb  + (size_t)M_ * E_;
  ushort_t* wkb = wqb + (size_t)E_ * E_;
  ushort_t* wvb = wkb + (size_t)E_ * E_;
  ushort_t* wpb = wvb + (size_t)E_ * E_;
  ushort_t* Qb  = wpb + (size_t)E_ * E_;
  ushort_t* Kb  = Qb  + (size_t)M_ * E_;
  ushort_t* Vb  = Kb  + (size_t)M_ * E_;
  ushort_t* Ab  = Vb  + (size_t)M_ * E_;

  conv_all<<<4096, 256, 0, stream>>>(x, Wq, Wk, Wv, Wp, xb, wqb, wkb, wvb, wpb);
  gemm_qkv<<<dim3(24, 32), 256, 0, stream>>>(xb, wqb, wkb, wvb, Qb, Kb, Vb);
  attn_mfma<<<512, 256, 0, stream>>>(Qb, Kb, Vb, Ab);
  gemm_out64<<<dim3(8, 64), 256, 0, stream>>>(Ab, wpb, bp, out);
}

// Round 9
// 135.084 us; speedup vs baseline: 18.4748x; 1.0150x over previous
//
#include <hip/hip_runtime.h>

#define T_ 2048
#define E_ 1024
#define H_ 16
#define D_ 64
#define M_ 4096   // B*T

typedef unsigned short ushort_t;
typedef __attribute__((ext_vector_type(8))) short bf16x8;
typedef __attribute__((ext_vector_type(4))) float f32x4;
typedef __attribute__((ext_vector_type(4))) unsigned short u16x4;
typedef __attribute__((ext_vector_type(8))) unsigned short u16x8;
typedef __attribute__((ext_vector_type(2))) unsigned int u32x2;

__device__ __forceinline__ ushort_t f2bf(float f) {
  union { float f; unsigned u; } v; v.f = f;
  unsigned r = v.u + 0x7FFFu + ((v.u >> 16) & 1u);
  return (ushort_t)(r >> 16);
}

__device__ __forceinline__ void gl16(const void* g, void* l) {
  __builtin_amdgcn_global_load_lds((const __attribute__((address_space(1))) void*)g,
                                   (__attribute__((address_space(3))) void*)l, 16, 0, 0);
}

// ---------------- all f32->bf16 conversions in ONE launch ----------------
__global__ __launch_bounds__(256)
void conv_all(const float* __restrict__ x,  const float* __restrict__ wq,
              const float* __restrict__ wk, const float* __restrict__ wv,
              const float* __restrict__ wp,
              ushort_t* __restrict__ xb,  ushort_t* __restrict__ wqb,
              ushort_t* __restrict__ wkb, ushort_t* __restrict__ wvb,
              ushort_t* __restrict__ wpb)
{
  const int id = blockIdx.x;
  const float* s; ushort_t* d; size_t off;
  if (id < 2048) { s = x; d = xb; off = (size_t)id * 2048; }
  else {
    int wsel = (id - 2048) >> 9, wid = (id - 2048) & 511;
    off = (size_t)wid * 2048;
    s = wsel == 0 ? wq : wsel == 1 ? wk : wsel == 2 ? wv : wp;
    d = wsel == 0 ? wqb : wsel == 1 ? wkb : wsel == 2 ? wvb : wpb;
  }
  size_t i = off + (size_t)threadIdx.x * 8;
  float4 a = *(const float4*)(s + i);
  float4 b = *(const float4*)(s + i + 4);
  u16x8 o;
  o[0]=f2bf(a.x); o[1]=f2bf(a.y); o[2]=f2bf(a.z); o[3]=f2bf(a.w);
  o[4]=f2bf(b.x); o[5]=f2bf(b.y); o[6]=f2bf(b.z); o[7]=f2bf(b.w);
  *(u16x8*)(d + i) = o;
}

// ------- 128x128x(K=1024) bf16 GEMM core, Y = A @ W^T, 2-phase pipelined -------
// Double-buffered LDS (As/Bs = [2][4096]); stage(k+1) issued BEFORE compute(k);
// single __syncthreads per K-step drains vmcnt (staged tile) + lgkm (frag reads).
__device__ __forceinline__ void gemm_core(const ushort_t* __restrict__ A,
                                          const ushort_t* __restrict__ W,
                                          int m0, int n0,
                                          ushort_t* As, ushort_t* Bs,
                                          f32x4 acc[4][4])
{
  const int t = threadIdx.x;
  const int lane = t & 63, w = t >> 6;
  const int g = lane >> 4, lq = lane & 15;
  const int wr = w >> 1, wc = w & 1;
  const int r0 = t >> 2;
  const int c0 = t & 3;
  const int ca0 = c0 ^ ((r0 >> 1) & 3);
  const int r1 = r0 + 64;
  const int ca1 = c0 ^ ((r1 >> 1) & 3);

  #pragma unroll
  for (int i = 0; i < 4; ++i)
    #pragma unroll
    for (int j = 0; j < 4; ++j) acc[i][j] = (f32x4){0.f,0.f,0.f,0.f};

  // prologue: stage k0=0 into buffer 0
  gl16(A + (size_t)(m0 + r0) * 1024 + ca0 * 8, As + t * 8);
  gl16(A + (size_t)(m0 + r1) * 1024 + ca1 * 8, As + 2048 + t * 8);
  gl16(W + (size_t)(n0 + r0) * 1024 + ca0 * 8, Bs + t * 8);
  gl16(W + (size_t)(n0 + r1) * 1024 + ca1 * 8, Bs + 2048 + t * 8);
  __syncthreads();

  int cur = 0;
  for (int k0 = 0; k0 < 1024; k0 += 32) {
    if (k0 + 32 < 1024) {             // prefetch next K-slice into other buffer
      const int nx = (cur ^ 1) * 4096;
      gl16(A + (size_t)(m0 + r0) * 1024 + k0 + 32 + ca0 * 8, As + nx + t * 8);
      gl16(A + (size_t)(m0 + r1) * 1024 + k0 + 32 + ca1 * 8, As + nx + 2048 + t * 8);
      gl16(W + (size_t)(n0 + r0) * 1024 + k0 + 32 + ca0 * 8, Bs + nx + t * 8);
      gl16(W + (size_t)(n0 + r1) * 1024 + k0 + 32 + ca1 * 8, Bs + nx + 2048 + t * 8);
    }
    const ushort_t* as = As + cur * 4096;
    const ushort_t* bs = Bs + cur * 4096;

    bf16x8 af[4], bfr[4];
    #pragma unroll
    for (int mi = 0; mi < 4; ++mi) {
      int row = wr * 64 + mi * 16 + lq;
      int ch = g ^ ((row >> 1) & 3);
      af[mi] = *(const bf16x8*)(as + row * 32 + ch * 8);
    }
    #pragma unroll
    for (int ni = 0; ni < 4; ++ni) {
      int row = wc * 64 + ni * 16 + lq;
      int ch = g ^ ((row >> 1) & 3);
      bfr[ni] = *(const bf16x8*)(bs + row * 32 + ch * 8);
    }
    __builtin_amdgcn_s_setprio(1);
    #pragma unroll
    for (int mi = 0; mi < 4; ++mi)
      #pragma unroll
      for (int ni = 0; ni < 4; ++ni)
        acc[mi][ni] = __builtin_amdgcn_mfma_f32_16x16x32_bf16(af[mi], bfr[ni], acc[mi][ni], 0, 0, 0);
    __builtin_amdgcn_s_setprio(0);

    __syncthreads();   // drains staged-tile vmcnt + frag-read lgkm; buffer swap safe
    cur ^= 1;
  }
}

// Fused QKV projection. grid.x 0..23: sel = x>>3 (Q,K,V), n0 = (x&7)*128.
__global__ __launch_bounds__(256)
void gemm_qkv(const ushort_t* __restrict__ xb,
              const ushort_t* __restrict__ wqb, const ushort_t* __restrict__ wkb,
              const ushort_t* __restrict__ wvb,
              ushort_t* __restrict__ Qd, ushort_t* __restrict__ Kd, ushort_t* __restrict__ Vd)
{
  __shared__ __align__(16) ushort_t As[2 * 4096];
  __shared__ __align__(16) ushort_t Bs[2 * 4096];
  const int bx = blockIdx.x;
  const int sel = bx >> 3;
  const int n0 = (bx & 7) * 128;
  const int m0 = blockIdx.y * 128;
  const ushort_t* W = sel == 0 ? wqb : (sel == 1 ? wkb : wvb);
  f32x4 acc[4][4];
  gemm_core(xb, W, m0, n0, As, Bs, acc);

  const int t = threadIdx.x, lane = t & 63, w = t >> 6;
  const int g = lane >> 4, lq = lane & 15, wr = w >> 1, wc = w & 1;
  const float scl = (sel == 0) ? 0.125f : 1.0f;
  ushort_t* dst = sel == 0 ? Qd : (sel == 1 ? Kd : Vd);
  #pragma unroll
  for (int mi = 0; mi < 4; ++mi)
    #pragma unroll
    for (int ni = 0; ni < 4; ++ni)
      #pragma unroll
      for (int r = 0; r < 4; ++r) {
        int m = m0 + wr * 64 + mi * 16 + 4 * g + r;
        int n = n0 + wc * 64 + ni * 16 + lq;
        int b = m >> 11, tt = m & (T_ - 1);
        int h = n >> 6, d = n & (D_ - 1);
        ushort_t v = f2bf(acc[mi][ni][r] * scl);
        if (sel < 2) dst[((size_t)(b * H_ + h) * T_ + tt) * D_ + d] = v;
        else         dst[((size_t)(b * H_ + h) * D_ + d) * T_ + tt] = v;
      }
}

// Output projection, 64x128 tiles, 2-phase pipelined: out = Ab @ Wp^T + bp. grid (8, 64).
__global__ __launch_bounds__(256)
void gemm_out64(const ushort_t* __restrict__ Ab, const ushort_t* __restrict__ wpb,
                const float* __restrict__ bias, float* __restrict__ out)
{
  __shared__ __align__(16) ushort_t As[2 * 2048];   // 2 x (64 x 32)
  __shared__ __align__(16) ushort_t Bs[2 * 4096];   // 2 x (128 x 32)
  const int t = threadIdx.x, lane = t & 63, w = t >> 6;
  const int g = lane >> 4, lq = lane & 15;
  const int n0 = blockIdx.x * 128;
  const int m0 = blockIdx.y * 64;
  const int r0 = t >> 2, c0 = t & 3;
  const int ca0 = c0 ^ ((r0 >> 1) & 3);
  const int r1 = r0 + 64;
  const int ca1 = c0 ^ ((r1 >> 1) & 3);

  f32x4 acc[4][2];
  #pragma unroll
  for (int i = 0; i < 4; ++i) { acc[i][0] = (f32x4){0.f,0.f,0.f,0.f}; acc[i][1] = (f32x4){0.f,0.f,0.f,0.f}; }

  // prologue: stage k0=0 into buffer 0
  gl16(Ab  + (size_t)(m0 + r0) * 1024 + ca0 * 8, As + t * 8);
  gl16(wpb + (size_t)(n0 + r0) * 1024 + ca0 * 8, Bs + t * 8);
  gl16(wpb + (size_t)(n0 + r1) * 1024 + ca1 * 8, Bs + 2048 + t * 8);
  __syncthreads();

  int cur = 0;
  for (int k0 = 0; k0 < 1024; k0 += 32) {
    if (k0 + 32 < 1024) {
      gl16(Ab  + (size_t)(m0 + r0) * 1024 + k0 + 32 + ca0 * 8, As + (cur ^ 1) * 2048 + t * 8);
      gl16(wpb + (size_t)(n0 + r0) * 1024 + k0 + 32 + ca0 * 8, Bs + (cur ^ 1) * 4096 + t * 8);
      gl16(wpb + (size_t)(n0 + r1) * 1024 + k0 + 32 + ca1 * 8, Bs + (cur ^ 1) * 4096 + 2048 + t * 8);
    }
    const ushort_t* as = As + cur * 2048;
    const ushort_t* bs = Bs + cur * 4096;

    bf16x8 af[4], bfr[2];
    #pragma unroll
    for (int mi = 0; mi < 4; ++mi) {
      int row = mi * 16 + lq;
      int ch = g ^ ((row >> 1) & 3);
      af[mi] = *(const bf16x8*)(as + row * 32 + ch * 8);
    }
    #pragma unroll
    for (int ni = 0; ni < 2; ++ni) {
      int row = w * 32 + ni * 16 + lq;
      int ch = g ^ ((row >> 1) & 3);
      bfr[ni] = *(const bf16x8*)(bs + row * 32 + ch * 8);
    }
    __builtin_amdgcn_s_setprio(1);
    #pragma unroll
    for (int mi = 0; mi < 4; ++mi)
      #pragma unroll
      for (int ni = 0; ni < 2; ++ni)
        acc[mi][ni] = __builtin_amdgcn_mfma_f32_16x16x32_bf16(af[mi], bfr[ni], acc[mi][ni], 0, 0, 0);
    __builtin_amdgcn_s_setprio(0);

    __syncthreads();
    cur ^= 1;
  }
  #pragma unroll
  for (int mi = 0; mi < 4; ++mi)
    #pragma unroll
    for (int ni = 0; ni < 2; ++ni)
      #pragma unroll
      for (int r = 0; r < 4; ++r) {
        int m = m0 + mi * 16 + 4 * g + r;
        int n = n0 + w * 32 + ni * 16 + lq;
        out[(size_t)m * E_ + n] = acc[mi][ni][r] + bias[n];
      }
}

// ---------------- MFMA flash attention v4 (R7-passing, exact): barrier-free ----------------
// QBLK=128 (4 waves x 32 q-rows). NO K/V LDS staging; LDS holds only per-wave Ps.
// Grid 512 linear; XCD-aware placement: xcd = i&7 owns heads 4x..4x+3; complementary
// qt pairing (chunks c and c+32 -> qt and 15-qt) => uniform 34 steps/CU.
__global__ __launch_bounds__(256, 2)
void attn_mfma(const ushort_t* __restrict__ Q, const ushort_t* __restrict__ K,
               const ushort_t* __restrict__ Vt, ushort_t* __restrict__ O)
{
  __shared__ __align__(16) ushort_t Ps[128 * 72];
  const int t = threadIdx.x, w = t >> 6, lane = t & 63;
  const int g = lane >> 4, lq = lane & 15;
  const int i = blockIdx.x;
  const int xcd = i & 7, chunk = i >> 3;
  const int bh = xcd * 4 + (chunk >> 4);
  const int qt = (chunk < 32) ? (chunk & 15) : (15 - (chunk & 15));
  const int q0 = qt * 128;
  const size_t qkbase = (size_t)bh * T_ * D_;
  const size_t vbase  = (size_t)bh * D_ * T_;

  // Q fragments directly to registers (read once)
  const int rowA = 32 * w + lq, rowB = rowA + 16;
  const int qgA = q0 + rowA, qgB = q0 + rowB;
  const bf16x8 qA0 = *(const bf16x8*)(Q + qkbase + (size_t)qgA * D_ + g * 8);
  const bf16x8 qA1 = *(const bf16x8*)(Q + qkbase + (size_t)qgA * D_ + 32 + g * 8);
  const bf16x8 qB0 = *(const bf16x8*)(Q + qkbase + (size_t)qgB * D_ + g * 8);
  const bf16x8 qB1 = *(const bf16x8*)(Q + qkbase + (size_t)qgB * D_ + 32 + g * 8);

  f32x4 accA[4], accB[4];
  #pragma unroll
  for (int db = 0; db < 4; ++db) { accA[db] = (f32x4){0.f,0.f,0.f,0.f}; accB[db] = (f32x4){0.f,0.f,0.f,0.f}; }
  float mA = -1e30f, lA = 0.f, mB = -1e30f, lB = 0.f;

  const int nt = 2 * qt + 2;

  for (int kt = 0; kt < nt; ++kt) {
    const int k0 = kt * 64;

    // issue ALL K and V fragment loads up front (L1/L2-resident; latency hides under QK+softmax)
    bf16x8 kf0[4], kf1[4], vf0[4], vf1[4];
    #pragma unroll
    for (int kb = 0; kb < 4; ++kb) {
      const ushort_t* kp = K + qkbase + (size_t)(k0 + kb * 16 + lq) * D_;
      kf0[kb] = *(const bf16x8*)(kp + g * 8);
      kf1[kb] = *(const bf16x8*)(kp + 32 + g * 8);
    }
    #pragma unroll
    for (int db = 0; db < 4; ++db) {
      const ushort_t* vp = Vt + vbase + (size_t)(db * 16 + lq) * T_ + k0;
      vf0[db] = *(const bf16x8*)(vp + g * 8);
      vf1[db] = *(const bf16x8*)(vp + 32 + g * 8);
    }

    // S^T = K . Q^T (each K fragment feeds both q sub-blocks)
    f32x4 stA[4], stB[4];
    __builtin_amdgcn_s_setprio(1);
    #pragma unroll
    for (int kb = 0; kb < 4; ++kb) {
      f32x4 zA = (f32x4){0.f,0.f,0.f,0.f};
      zA = __builtin_amdgcn_mfma_f32_16x16x32_bf16(kf0[kb], qA0, zA, 0, 0, 0);
      zA = __builtin_amdgcn_mfma_f32_16x16x32_bf16(kf1[kb], qA1, zA, 0, 0, 0);
      stA[kb] = zA;
      f32x4 zB = (f32x4){0.f,0.f,0.f,0.f};
      zB = __builtin_amdgcn_mfma_f32_16x16x32_bf16(kf0[kb], qB0, zB, 0, 0, 0);
      zB = __builtin_amdgcn_mfma_f32_16x16x32_bf16(kf1[kb], qB1, zB, 0, 0, 0);
      stB[kb] = zB;
    }
    __builtin_amdgcn_s_setprio(0);

    if (kt >= nt - 2) {                      // only diagonal-adjacent tiles mask
      #pragma unroll
      for (int kb = 0; kb < 4; ++kb)
        #pragma unroll
        for (int r = 0; r < 4; ++r) {
          int kg = k0 + kb * 16 + 4 * g + r;
          if (kg > qgA) stA[kb][r] = -1e30f;
          if (kg > qgB) stB[kb][r] = -1e30f;
        }
    }

    float tmA = -1e30f, tmB = -1e30f;
    #pragma unroll
    for (int kb = 0; kb < 4; ++kb)
      #pragma unroll
      for (int r = 0; r < 4; ++r) { tmA = fmaxf(tmA, stA[kb][r]); tmB = fmaxf(tmB, stB[kb][r]); }
    tmA = fmaxf(tmA, __shfl_xor(tmA, 16)); tmA = fmaxf(tmA, __shfl_xor(tmA, 32));
    tmB = fmaxf(tmB, __shfl_xor(tmB, 16)); tmB = fmaxf(tmB, __shfl_xor(tmB, 32));

    // defer-max: only rescale when a row's max grew by > 8 (wave-uniform branch)
    if (!__all((tmA <= mA + 8.f) && (tmB <= mB + 8.f))) {
      float mnA = fmaxf(mA, tmA), mnB = fmaxf(mB, tmB);
      float alA = __expf(mA - mnA), alB = __expf(mB - mnB);
      mA = mnA; mB = mnB;
      lA *= alA; lB *= alB;
      float alAr[4], alBr[4];
      #pragma unroll
      for (int r = 0; r < 4; ++r) { alAr[r] = __shfl(alA, 4 * g + r); alBr[r] = __shfl(alB, 4 * g + r); }
      #pragma unroll
      for (int db = 0; db < 4; ++db)
        #pragma unroll
        for (int r = 0; r < 4; ++r) { accA[db][r] *= alAr[r]; accB[db][r] *= alBr[r]; }
    }

    float tsA = 0.f, tsB = 0.f;
    #pragma unroll
    for (int kb = 0; kb < 4; ++kb) {
      float pA0 = __expf(stA[kb][0] - mA), pA1 = __expf(stA[kb][1] - mA);
      float pA2 = __expf(stA[kb][2] - mA), pA3 = __expf(stA[kb][3] - mA);
      float pB0 = __expf(stB[kb][0] - mB), pB1 = __expf(stB[kb][1] - mB);
      float pB2 = __expf(stB[kb][2] - mB), pB3 = __expf(stB[kb][3] - mB);
      tsA += (pA0 + pA1) + (pA2 + pA3);
      tsB += (pB0 + pB1) + (pB2 + pB3);
      unsigned aLo, aHi, bLo, bHi;
      asm("v_cvt_pk_bf16_f32 %0, %1, %2" : "=v"(aLo) : "v"(pA0), "v"(pA1));
      asm("v_cvt_pk_bf16_f32 %0, %1, %2" : "=v"(aHi) : "v"(pA2), "v"(pA3));
      asm("v_cvt_pk_bf16_f32 %0, %1, %2" : "=v"(bLo) : "v"(pB0), "v"(pB1));
      asm("v_cvt_pk_bf16_f32 %0, %1, %2" : "=v"(bHi) : "v"(pB2), "v"(pB3));
      *(u32x2*)(Ps + rowA * 72 + kb * 16 + 4 * g) = (u32x2){aLo, aHi};
      *(u32x2*)(Ps + rowB * 72 + kb * 16 + 4 * g) = (u32x2){bLo, bHi};
    }
    tsA += __shfl_xor(tsA, 16); tsA += __shfl_xor(tsA, 32);
    tsB += __shfl_xor(tsB, 16); tsB += __shfl_xor(tsB, 32);
    lA += tsA; lB += tsB;

    asm volatile("s_waitcnt lgkmcnt(0)" ::: "memory");   // own-wave Ps writes visible
    bf16x8 paA0 = *(const bf16x8*)(Ps + rowA * 72 + g * 8);
    bf16x8 paA1 = *(const bf16x8*)(Ps + rowA * 72 + 32 + g * 8);
    bf16x8 paB0 = *(const bf16x8*)(Ps + rowB * 72 + g * 8);
    bf16x8 paB1 = *(const bf16x8*)(Ps + rowB * 72 + 32 + g * 8);

    __builtin_amdgcn_s_setprio(1);
    #pragma unroll
    for (int db = 0; db < 4; ++db) {
      accA[db] = __builtin_amdgcn_mfma_f32_16x16x32_bf16(paA0, vf0[db], accA[db], 0, 0, 0);
      accA[db] = __builtin_amdgcn_mfma_f32_16x16x32_bf16(paA1, vf1[db], accA[db], 0, 0, 0);
      accB[db] = __builtin_amdgcn_mfma_f32_16x16x32_bf16(paB0, vf0[db], accB[db], 0, 0, 0);
      accB[db] = __builtin_amdgcn_mfma_f32_16x16x32_bf16(paB1, vf1[db], accB[db], 0, 0, 0);
    }
    __builtin_amdgcn_s_setprio(0);
  }

  float invA = 1.0f / lA, invB = 1.0f / lB;
  float liA[4], liB[4];
  #pragma unroll
  for (int r = 0; r < 4; ++r) { liA[r] = __shfl(invA, 4 * g + r); liB[r] = __shfl(invB, 4 * g + r); }
  const int b = bh >> 4, h = bh & 15;
  #pragma unroll
  for (int db = 0; db < 4; ++db)
    #pragma unroll
    for (int r = 0; r < 4; ++r) {
      int mAo = q0 + 32 * w + 4 * g + r;
      int mBo = mAo + 16;
      O[((size_t)(b * T_ + mAo)) * E_ + h * 64 + db * 16 + lq] = f2bf(accA[db][r] * liA[r]);
      O[((size_t)(b * T_ + mBo)) * E_ + h * 64 + db * 16 + lq] = f2bf(accB[db][r] * liB[r]);
    }
}

extern "C" void kernel_launch(void* const* d_in, const int* in_sizes, int n_in,
                              void* d_out, int out_size, void* d_ws, size_t ws_size,
                              hipStream_t stream) {
  const float* x  = (const float*)d_in[0];
  const float* Wq = (const float*)d_in[1];
  const float* Wk = (const float*)d_in[2];
  const float* Wv = (const float*)d_in[3];
  const float* Wp = (const float*)d_in[4];
  const float* bp = (const float*)d_in[5];
  float* out = (float*)d_out;

  ushort_t* ws  = (ushort_t*)d_ws;
  ushort_t* xb  = ws;
  ushort_t* wqb = xb  + (size_t)M_ * E_;
  ushort_t* wkb = wqb + (size_t)E_ * E_;
  ushort_t* wvb = wkb + (size_t)E_ * E_;
  ushort_t* wpb = wvb + (size_t)E_ * E_;
  ushort_t* Qb  = wpb + (size_t)E_ * E_;
  ushort_t* Kb  = Qb  + (size_t)M_ * E_;
  ushort_t* Vb  = Kb  + (size_t)M_ * E_;
  ushort_t* Ab  = Vb  + (size_t)M_ * E_;

  conv_all<<<4096, 256, 0, stream>>>(x, Wq, Wk, Wv, Wp, xb, wqb, wkb, wvb, wpb);
  gemm_qkv<<<dim3(24, 32), 256, 0, stream>>>(xb, wqb, wkb, wvb, Qb, Kb, Vb);
  attn_mfma<<<512, 256, 0, stream>>>(Qb, Kb, Vb, Ab);
  gemm_out64<<<dim3(8, 64), 256, 0, stream>>>(Ab, wpb, bp, out);
}